// Round 14
// baseline (510.880 us; speedup 1.0000x reference)
//
#include <hip/hip_runtime.h>
#include <hip/hip_bf16.h>

// Problem constants
#define Bq   64
#define Tt   512
#define DIN  512
#define Ss   8
#define HSs  128
#define Hh   8
#define Mm   1024
#define KDd  128
#define NGg  2048
#define KVS  3072   // fused kvx row stride (2048 kv + 1024 x)

typedef __attribute__((ext_vector_type(8))) short bf16x8;
typedef __attribute__((ext_vector_type(4))) float f32x4;

__device__ __forceinline__ ushort f2b(float f) {
    union { float f; unsigned u; } v; v.f = f;
    unsigned r = v.u + 0x7fffu + ((v.u >> 16) & 1u);   // RNE
    return (ushort)(r >> 16);
}
__device__ __forceinline__ float b2f(ushort b) {
    union { unsigned u; float f; } v; v.u = ((unsigned)b) << 16;
    return v.f;
}
__device__ __forceinline__ float blo(unsigned u) {
    union { unsigned u; float f; } v; v.u = u << 16; return v.f;
}
__device__ __forceinline__ float bhi(unsigned u) {
    union { unsigned u; float f; } v; v.u = u & 0xffff0000u; return v.f;
}

#define GLOAD_LDS16(g, l) __builtin_amdgcn_global_load_lds( \
    (const __attribute__((address_space(1))) void*)(g),     \
    (__attribute__((address_space(3))) void*)(l), 16, 0, 0)

#define LGKM0 do { asm volatile("s_waitcnt lgkmcnt(0)" ::: "memory");         \
                   __builtin_amdgcn_sched_barrier(0); } while (0)

// ---------------------------------------------------------------------------
// 256x256 bf16 MFMA GEMM (r12 gray-code schedule — best measured), BK=64,
// 512 threads (8 waves as 2x4), minimal 24 ds_read_b128/wave/tile with the
// incremental read batches overlapped under MFMA clusters.
// T1 bijective XCD swizzle; T2 both-sides XOR swizzle (rule #21).
// Requires rows%256==0, N%256==0, K%64==0, K/64 >= 2.
// ---------------------------------------------------------------------------
template<int OUT_BF16>
__global__ __launch_bounds__(512)
void gemm_big(const ushort* __restrict__ A, const ushort* __restrict__ Bt,
              const float* __restrict__ bias, void* __restrict__ Cout,
              int ldc, int Kdim)
{
    extern __shared__ __align__(16) char lds[];   // 131072 bytes

    const int tid  = threadIdx.x;
    const int wid  = tid >> 6;
    const int lane = tid & 63;
    const int wy   = wid >> 2;
    const int wx   = wid & 3;

    const int gx   = gridDim.x;
    const int nwg  = gx * gridDim.y;
    const int orig = blockIdx.y * gx + blockIdx.x;
    const int q8   = nwg >> 3, r8 = nwg & 7;
    const int xcd  = orig & 7, idx8 = orig >> 3;
    const int swz  = (xcd < r8 ? xcd * (q8 + 1)
                               : r8 * (q8 + 1) + (xcd - r8) * q8) + idx8;
    const int row0 = (swz / gx) * 256;
    const int col0 = (swz % gx) * 256;

    const int NT = Kdim >> 6;

    const int sr = tid >> 3;
    const int sq = (tid & 7) ^ (sr & 7);
    const ushort* Asrc = A  + (size_t)(row0 + sr) * Kdim + sq * 8;
    const ushort* Bsrc = Bt + (size_t)(col0 + sr) * Kdim + sq * 8;
    const int ldsw = wid * 1024;

    auto stage = [&](int isB, int U, int h) {
        const ushort* s = (isB ? Bsrc : Asrc) + (size_t)h * 128 * Kdim
                        + (size_t)U * 64;
        char* d = lds + (isB ? 65536 : 0) + ((((U) & 1) * 2 + h) << 14) + ldsw;
        GLOAD_LDS16(s, d);
        GLOAD_LDS16(s + (size_t)64 * Kdim, d + 8192);
    };
    auto stage_tile = [&](int U) {
        stage(0, U, 0); stage(0, U, 1); stage(1, U, 0); stage(1, U, 1);
    };

    const int l15   = lane & 15;
    const int s0_16 = (((lane >> 4)) ^ (lane & 7)) << 4;
    const int s1_16 = ((4 + (lane >> 4)) ^ (lane & 7)) << 4;
    const int aoff  = wy * 8192 + l15 * 128;
    const int boff  = wx * 4096 + l15 * 128;

    f32x4 acc[4][4][2];
#pragma unroll
    for (int p = 0; p < 4; ++p)
#pragma unroll
        for (int m = 0; m < 4; ++m)
#pragma unroll
            for (int n = 0; n < 2; ++n) acc[p][m][n] = (f32x4){0.f,0.f,0.f,0.f};

#define MFMAQ(P, AH, BH)                                                      \
    {                                                                         \
        __builtin_amdgcn_s_setprio(1);                                        \
        _Pragma("unroll")                                                     \
        for (int kk = 0; kk < 2; ++kk)                                        \
            _Pragma("unroll")                                                 \
            for (int m = 0; m < 4; ++m)                                       \
                _Pragma("unroll")                                             \
                for (int n = 0; n < 2; ++n)                                   \
                    acc[P][m][n] = __builtin_amdgcn_mfma_f32_16x16x32_bf16(   \
                        AH[kk][m], BH[kk][n], acc[P][m][n], 0, 0, 0);         \
        __builtin_amdgcn_s_setprio(0);                                        \
    }

    stage_tile(0);
    stage_tile(1);
    asm volatile("s_waitcnt vmcnt(8)" ::: "memory");
    __builtin_amdgcn_s_barrier();
    asm volatile("" ::: "memory");

    for (int U = 0; U < NT; ++U) {
        const char* Ab = lds + ((U & 1) << 15);
        const char* Bb = lds + 65536 + ((U & 1) << 15);

        bf16x8 a0[2][4], a1[2][4];
        bf16x8 b0[2][2], b1[2][2];

#pragma unroll
        for (int m = 0; m < 4; ++m) {
            a0[0][m] = *(const bf16x8*)(Ab + aoff + s0_16 + m * 2048);
            a0[1][m] = *(const bf16x8*)(Ab + aoff + s1_16 + m * 2048);
        }
#pragma unroll
        for (int n = 0; n < 2; ++n) {
            b0[0][n] = *(const bf16x8*)(Bb + boff + s0_16 + n * 2048);
            b0[1][n] = *(const bf16x8*)(Bb + boff + s1_16 + n * 2048);
        }
        LGKM0;

#pragma unroll
        for (int m = 0; m < 4; ++m) {
            a1[0][m] = *(const bf16x8*)(Ab + 16384 + aoff + s0_16 + m * 2048);
            a1[1][m] = *(const bf16x8*)(Ab + 16384 + aoff + s1_16 + m * 2048);
        }
        MFMAQ(0, a0, b0);
        LGKM0;

#pragma unroll
        for (int n = 0; n < 2; ++n) {
            b1[0][n] = *(const bf16x8*)(Bb + 16384 + boff + s0_16 + n * 2048);
            b1[1][n] = *(const bf16x8*)(Bb + 16384 + boff + s1_16 + n * 2048);
        }
        MFMAQ(1, a1, b0);
        LGKM0;

        __builtin_amdgcn_s_barrier();            // B1
        asm volatile("" ::: "memory");
        if (U + 2 < NT) stage_tile(U + 2);

        MFMAQ(3, a1, b1);
        MFMAQ(2, a0, b1);

        if (U + 2 < NT) asm volatile("s_waitcnt vmcnt(8)" ::: "memory");
        else            asm volatile("s_waitcnt vmcnt(0)" ::: "memory");
        __builtin_amdgcn_s_barrier();            // B2
        asm volatile("" ::: "memory");
    }
#undef MFMAQ

#pragma unroll
    for (int p = 0; p < 4; ++p) {
        const int rb = row0 + (p & 1) * 128 + wy * 64 + (lane >> 4) * 4;
        const int cb = col0 + (p >> 1) * 128 + wx * 32 + (lane & 15);
#pragma unroll
        for (int n = 0; n < 2; ++n) {
            const float bv = bias[cb + n * 16];
#pragma unroll
            for (int m = 0; m < 4; ++m) {
#pragma unroll
                for (int r = 0; r < 4; ++r) {
                    const float v = acc[p][m][n][r] + bv;
                    const size_t off = (size_t)(rb + m * 16 + r) * ldc + cb + n * 16;
                    if (OUT_BF16) ((ushort*)Cout)[off] = f2b(v);
                    else          ((float*)Cout)[off]  = v;
                }
            }
        }
    }
}

// ---------------------------------------------------------------------------
// Small 128x128 bf16 MFMA GEMM: BK=32, 4 waves, 64x64/wave, 16 KB LDS.
// ---------------------------------------------------------------------------
template<int OUT_BF16, int RELU>
__global__ __launch_bounds__(256)
void gemm_sm(const ushort* __restrict__ A, const ushort* __restrict__ Bt,
             const float* __restrict__ bias, void* __restrict__ Cout,
             int ldc, int Kdim)
{
    __shared__ __align__(16) ushort As[128 * 32];   // 8 KB
    __shared__ __align__(16) ushort Bs[128 * 32];   // 8 KB

    const int tid  = threadIdx.x;
    const int w    = tid >> 6;
    const int lane = tid & 63;

    const int gx   = gridDim.x;
    const int nwg  = gx * gridDim.y;
    const int orig = blockIdx.y * gx + blockIdx.x;
    const int q8   = nwg >> 3, r8 = nwg & 7;
    const int xcd  = orig & 7, idx8 = orig >> 3;
    const int swz  = (xcd < r8 ? xcd * (q8 + 1)
                               : r8 * (q8 + 1) + (xcd - r8) * q8) + idx8;
    const int row0 = (swz / gx) * 128;
    const int col0 = (swz % gx) * 128;
    const int wr   = w >> 1, wc = w & 1;

    f32x4 acc[4][4];
#pragma unroll
    for (int i = 0; i < 4; ++i)
#pragma unroll
        for (int j = 0; j < 4; ++j) acc[i][j] = (f32x4){0.f, 0.f, 0.f, 0.f};

    const ushort* Ag = A  + (size_t)(row0 + (tid >> 2)) * Kdim + (tid & 3) * 8;
    const ushort* Bg = Bt + (size_t)(col0 + (tid >> 2)) * Kdim + (tid & 3) * 8;

    for (int k0 = 0; k0 < Kdim; k0 += 32) {
        __syncthreads();
#pragma unroll
        for (int is = 0; is < 2; ++is)
            GLOAD_LDS16(Ag + (size_t)is * 64 * Kdim + k0,
                        (char*)As + (is * 256 + w * 64) * 16);
#pragma unroll
        for (int is = 0; is < 2; ++is)
            GLOAD_LDS16(Bg + (size_t)is * 64 * Kdim + k0,
                        (char*)Bs + (is * 256 + w * 64) * 16);
        asm volatile("s_waitcnt vmcnt(0)" ::: "memory");
        __syncthreads();

        bf16x8 a[4], b[4];
#pragma unroll
        for (int i = 0; i < 4; ++i) {
            a[i] = *(const bf16x8*)&As[(wr * 64 + i * 16 + (lane & 15)) * 32 + (lane >> 4) * 8];
            b[i] = *(const bf16x8*)&Bs[(wc * 64 + i * 16 + (lane & 15)) * 32 + (lane >> 4) * 8];
        }
#pragma unroll
        for (int i = 0; i < 4; ++i)
#pragma unroll
            for (int j = 0; j < 4; ++j)
                acc[i][j] = __builtin_amdgcn_mfma_f32_16x16x32_bf16(a[i], b[j], acc[i][j], 0, 0, 0);
    }

    float bsv[4];
#pragma unroll
    for (int j = 0; j < 4; ++j) bsv[j] = bias[col0 + wc * 64 + j * 16 + (lane & 15)];
#pragma unroll
    for (int i = 0; i < 4; ++i) {
        const int row = row0 + wr * 64 + i * 16 + (lane >> 4) * 4;
        const int col = col0 + wc * 64 + (lane & 15);
#pragma unroll
        for (int r = 0; r < 4; ++r) {
            const size_t off = (size_t)(row + r) * ldc + col;
#pragma unroll
            for (int j = 0; j < 4; ++j) {
                float vv = acc[i][j][r] + bsv[j];
                if (RELU) vv = fmaxf(vv, 0.f);
                if (OUT_BF16) ((ushort*)Cout)[off + j * 16] = f2b(vv);
                else          ((float*)Cout)[off + j * 16]  = vv;
            }
        }
    }
}

// ---------------------------------------------------------------------------
// gm MFMA: per-slot GEMM gm[b][s][n] = tanh16[b][s][:] @ glWT[s][n][:] + gl_b[s][n]
// BM=64 (all b), BN=128, BK=32, 256 thr (4 waves, each 64x32 output).
// grid (NGg/128, 1, Ss). A tanh16 [64][8][1024] bf16; glWT [8][2048][1024] bf16.
// Memory-bound (reads 4 MB of glWT per block-col); simple 2-barrier loop.
// ---------------------------------------------------------------------------
__global__ __launch_bounds__(256)
void gm_mfma(const ushort* __restrict__ tanhA, const ushort* __restrict__ glWT,
             const float* __restrict__ gl_b, float* __restrict__ gm)
{
    __shared__ __align__(16) ushort As[64 * 32];    // 4 KB
    __shared__ __align__(16) ushort Bs[128 * 32];   // 8 KB

    const int tid  = threadIdx.x;
    const int w    = tid >> 6;
    const int lane = tid & 63;
    const int s    = blockIdx.z;
    const int col0 = blockIdx.x * 128;

    f32x4 acc[4][2];
#pragma unroll
    for (int i = 0; i < 4; ++i)
#pragma unroll
        for (int j = 0; j < 2; ++j) acc[i][j] = (f32x4){0.f, 0.f, 0.f, 0.f};

    // staging addresses: thread t -> row t>>2, k-quarter (t&3)*8
    const ushort* Ag = tanhA + (size_t)(tid >> 2) * (Ss * Mm) + s * Mm + (tid & 3) * 8;
    const ushort* Bg = glWT + (size_t)s * NGg * Mm
                     + (size_t)(col0 + (tid >> 2)) * Mm + (tid & 3) * 8;

    for (int k0 = 0; k0 < Mm; k0 += 32) {
        __syncthreads();
        GLOAD_LDS16(Ag + k0, (char*)As + w * 1024);
#pragma unroll
        for (int is = 0; is < 2; ++is)
            GLOAD_LDS16(Bg + (size_t)is * 64 * Mm + k0,
                        (char*)Bs + (is * 256 + w * 64) * 16);
        asm volatile("s_waitcnt vmcnt(0)" ::: "memory");
        __syncthreads();

        bf16x8 a[4], b[2];
#pragma unroll
        for (int i = 0; i < 4; ++i)
            a[i] = *(const bf16x8*)&As[(i * 16 + (lane & 15)) * 32 + (lane >> 4) * 8];
#pragma unroll
        for (int j = 0; j < 2; ++j)
            b[j] = *(const bf16x8*)&Bs[(w * 32 + j * 16 + (lane & 15)) * 32 + (lane >> 4) * 8];
#pragma unroll
        for (int i = 0; i < 4; ++i)
#pragma unroll
            for (int j = 0; j < 2; ++j)
                acc[i][j] = __builtin_amdgcn_mfma_f32_16x16x32_bf16(a[i], b[j], acc[i][j], 0, 0, 0);
    }

    // epilogue: b-row = i*16 + (lane>>4)*4 + r ; col = col0 + w*32 + j*16 + (lane&15)
#pragma unroll
    for (int j = 0; j < 2; ++j) {
        const int col = col0 + w * 32 + j * 16 + (lane & 15);
        const float bv = gl_b[s * NGg + col];
#pragma unroll
        for (int i = 0; i < 4; ++i) {
#pragma unroll
            for (int r = 0; r < 4; ++r) {
                const int b = i * 16 + (lane >> 4) * 4 + r;
                gm[(size_t)b * (Ss * NGg) + (size_t)s * NGg + col] = acc[i][j][r] + bv;
            }
        }
    }
}

// ---------------------------------------------------------------------------
// transpose + convert: out[C][R] bf16 = in[R][C] fp32   (R,C multiples of 32)
// ---------------------------------------------------------------------------
__global__ __launch_bounds__(256)
void transpose_to_bf16(const float* __restrict__ in, ushort* __restrict__ out,
                       int R, int C)
{
    __shared__ float t[32][33];
    const int c0 = blockIdx.x * 32, r0 = blockIdx.y * 32;
    const int tx = threadIdx.x & 31, ty = threadIdx.x >> 5;   // 32 x 8
#pragma unroll
    for (int i = 0; i < 32; i += 8)
        t[ty + i][tx] = in[(size_t)(r0 + ty + i) * C + c0 + tx];
    __syncthreads();
#pragma unroll
    for (int i = 0; i < 32; i += 8)
        out[(size_t)(c0 + ty + i) * R + r0 + tx] = f2b(t[tx][ty + i]);
}

// elementwise fp32 -> bf16 (n divisible by 1024)
__global__ __launch_bounds__(256)
void conv_bf16(const float* __restrict__ in, ushort* __restrict__ out)
{
    const int i = blockIdx.x * 256 + threadIdx.x;
    float4 v = ((const float4*)in)[i];
    ushort4 o;
    o.x = f2b(v.x); o.y = f2b(v.y); o.z = f2b(v.z); o.w = f2b(v.w);
    ((ushort4*)out)[i] = o;
}

// elementwise tanh(fp32) -> bf16 (n divisible by 1024)
__global__ __launch_bounds__(256)
void tanh_bf16(const float* __restrict__ in, ushort* __restrict__ out)
{
    const int i = blockIdx.x * 256 + threadIdx.x;
    float4 v = ((const float4*)in)[i];
    ushort4 o;
    o.x = f2b(tanhf(v.x)); o.y = f2b(tanhf(v.y));
    o.z = f2b(tanhf(v.z)); o.w = f2b(tanhf(v.w));
    ((ushort4*)out)[i] = o;
}

// zero-fill n floats (n divisible by 256)
__global__ __launch_bounds__(256)
void fill0(float* __restrict__ o)
{
    o[blockIdx.x * 256 + threadIdx.x] = 0.f;
}

// copy 1024 floats (bp -> tail of fused bias)
__global__ __launch_bounds__(256)
void copy_vec(const float* __restrict__ in, float* __restrict__ o)
{
    const int i = blockIdx.x * 256 + threadIdx.x;
    o[i] = in[i];
}

// ---------------------------------------------------------------------------
// fuse_bias: outb[n] = sum_m bp[m] * Wkv[m][n] + bkv[n], n in [0, 2048).
// ---------------------------------------------------------------------------
__global__ __launch_bounds__(256)
void fuse_bias(const float* __restrict__ bp,
               const float* __restrict__ Wk, const float* __restrict__ Wv,
               const float* __restrict__ bk, const float* __restrict__ bv,
               float* __restrict__ outb)
{
    __shared__ float red[4][64];
    const int col = threadIdx.x & 63;
    const int mq  = threadIdx.x >> 6;
    const int n   = blockIdx.x * 64 + col;
    const float* W = (n < Mm) ? Wk : Wv;
    const int nn   = n & (Mm - 1);
    float s = 0.f;
    for (int m = mq * 256; m < mq * 256 + 256; ++m)
        s += bp[m] * W[(size_t)m * Mm + nn];
    red[mq][col] = s;
    __syncthreads();
    if (mq == 0) {
        float t = red[0][col] + red[1][col] + red[2][col] + red[3][col];
        outb[n] = t + ((n < Mm) ? bk[nn] : bv[nn]);
    }
}

// ---------------------------------------------------------------------------
// Split-K fp32 GEMM: partials P[zz][Mrows][Ncols], zz = batch*SPLITK + ks.
// ---------------------------------------------------------------------------
template<int BM, int BN, int BK, int TM, int TN, int SPLITK, bool TANH_A>
__global__ __launch_bounds__(256)
void gemm_f32_sk(const float* __restrict__ A, int lda, long long sA,
                 const float* __restrict__ B, int ldb, long long sB,
                 float* __restrict__ P, int Mrows, int Ncols, int Kdim)
{
    constexpr int TX = BN / TN;
    constexpr int TY = BM / TM;
    static_assert(TX * TY == 256, "256 threads");
    constexpr int KC4   = BK / 4;
    constexpr int A_PER = (BM * BK / 4) / 256;
    constexpr int B_PER = (BK * BN / 4) / 256;

    __shared__ float As[BK][BM + 4];
    __shared__ float Bs[BK][BN];

    const int tid = threadIdx.x;
    const int tx  = tid % TX;
    const int ty  = tid / TX;
    const int zz  = blockIdx.z;
    const int zb  = zz / SPLITK;
    const int ks  = zz % SPLITK;
    A += (long long)zb * sA;
    B += (long long)zb * sB;
    const int Kslice = Kdim / SPLITK;
    const int kbeg = ks * Kslice, kend = kbeg + Kslice;
    const int row0 = blockIdx.y * BM;
    const int col0 = blockIdx.x * BN;

    float acc[TM][TN];
#pragma unroll
    for (int i = 0; i < TM; ++i)
#pragma unroll
        for (int j = 0; j < TN; ++j) acc[i][j] = 0.f;

    for (int k0 = kbeg; k0 < kend; k0 += BK) {
        __syncthreads();
#pragma unroll
        for (int l = 0; l < A_PER; ++l) {
            int idx = tid + l * 256;
            int ar  = idx / KC4;
            int ac  = (idx % KC4) * 4;
            float4 va = *(const float4*)&A[(long long)(row0 + ar) * lda + k0 + ac];
            if (TANH_A) {
                va.x = tanhf(va.x); va.y = tanhf(va.y);
                va.z = tanhf(va.z); va.w = tanhf(va.w);
            }
            As[ac + 0][ar] = va.x;
            As[ac + 1][ar] = va.y;
            As[ac + 2][ar] = va.z;
            As[ac + 3][ar] = va.w;
        }
#pragma unroll
        for (int l = 0; l < B_PER; ++l) {
            int idx = tid + l * 256;
            int br  = idx / (BN / 4);
            int bc  = (idx % (BN / 4)) * 4;
            *(float4*)&Bs[br][bc] = *(const float4*)&B[(long long)(k0 + br) * ldb + col0 + bc];
        }
        __syncthreads();
#pragma unroll
        for (int k = 0; k < BK; ++k) {
            float a[TM], b[TN];
#pragma unroll
            for (int i = 0; i < TM; i += 4)
                *(float4*)&a[i] = *(const float4*)&As[k][ty * TM + i];
#pragma unroll
            for (int j = 0; j < TN; j += 4)
                *(float4*)&b[j] = *(const float4*)&Bs[k][tx * TN + j];
#pragma unroll
            for (int i = 0; i < TM; ++i)
#pragma unroll
                for (int j = 0; j < TN; ++j)
                    acc[i][j] = fmaf(a[i], b[j], acc[i][j]);
        }
    }

    float* Pz = P + (size_t)zz * Mrows * Ncols;
#pragma unroll
    for (int i = 0; i < TM; ++i) {
        const size_t prow = (size_t)(row0 + ty * TM + i) * Ncols;
#pragma unroll
        for (int j = 0; j < TN; j += 4)
            *(float4*)&Pz[prow + col0 + tx * TN + j] = *(const float4*)&acc[i][j];
    }
}

// ---------------------------------------------------------------------------
// sk_reduce: C[batch][row][col] = (relu?)( sum_ks P + bias[batch][col] )
// ---------------------------------------------------------------------------
template<int SPLITK, bool RELU>
__global__ __launch_bounds__(256)
void sk_reduce(const float* __restrict__ P, const float* __restrict__ bias,
               long long sBias, float* __restrict__ C, int ldc, long long sC,
               int pb4, int Ncols)
{
    const int gid = blockIdx.x * 256 + threadIdx.x;
    const int batch = gid / pb4;
    const int r4    = gid % pb4;
    const float4* Pb = (const float4*)P + (size_t)batch * SPLITK * pb4 + r4;
    float4 s = Pb[0];
#pragma unroll
    for (int ks = 1; ks < SPLITK; ++ks) {
        float4 p = Pb[(size_t)ks * pb4];
        s.x += p.x; s.y += p.y; s.z += p.z; s.w += p.w;
    }
    const int col = (r4 * 4) % Ncols;
    const int row = (r4 * 4) / Ncols;
    float4 bv = *(const float4*)&bias[batch * sBias + col];
    s.x += bv.x; s.y += bv.y; s.z += bv.z; s.w += bv.w;
    if (RELU) {
        s.x = fmaxf(s.x, 0.f); s.y = fmaxf(s.y, 0.f);
        s.z = fmaxf(s.z, 0.f); s.w = fmaxf(s.w, 0.f);
    }
    *(float4*)&C[(size_t)batch * sC + (size_t)row * ldc + col] = s;
}

// ---------------------------------------------------------------------------
// gi_mean[b, m] = (1/T) * sum_t relu(rl_w[m] * kvx[b, t, 2048+m])
// ---------------------------------------------------------------------------
__global__ __launch_bounds__(256)
void gi_reduce(const ushort* __restrict__ kvx, const float* __restrict__ rl_w,
               float* __restrict__ gi_mean)
{
    const int b    = blockIdx.x / (Mm / 256);
    const int mblk = blockIdx.x % (Mm / 256);
    const int m    = mblk * 256 + threadIdx.x;
    const float w  = rl_w[m];
    const ushort* xp = kvx + (size_t)b * Tt * KVS + 2048 + m;
    float sum = 0.f;
    for (int t = 0; t < Tt; ++t)
        sum += fmaxf(w * b2f(xp[(size_t)t * KVS]), 0.f);
    gi_mean[b * Mm + m] = sum * (1.f / (float)Tt);
}

// ---------------------------------------------------------------------------
// Fused attention per (b, h): q fp32 [.,S,M]; kvx bf16 [.,T,KVS]
// ---------------------------------------------------------------------------
__global__ __launch_bounds__(256)
void attn_kernel(const float* __restrict__ q, const ushort* __restrict__ kv,
                 float* __restrict__ att)
{
    const int b = blockIdx.x / Hh;
    const int h = blockIdx.x % Hh;
    const int tid = threadIdx.x;

    __shared__ float qs[Ss][KDd];
    __shared__ float sc[Ss][Tt];

    {
        int s  = tid / 32;
        int d4 = (tid % 32) * 4;
        float4 qv = *(const float4*)&q[((size_t)(b * Ss + s)) * Mm + h * KDd + d4];
        qs[s][d4 + 0] = qv.x; qs[s][d4 + 1] = qv.y;
        qs[s][d4 + 2] = qv.z; qs[s][d4 + 3] = qv.w;
    }
    __syncthreads();

#pragma unroll
    for (int half = 0; half < 2; ++half) {
        const int t = tid + half * 256;
        const ushort* kr = kv + ((size_t)(b * Tt + t)) * KVS + h * KDd;
        float acc[Ss];
#pragma unroll
        for (int s = 0; s < Ss; ++s) acc[s] = 0.f;
        for (int d = 0; d < KDd; d += 8) {
            uint4 u = *(const uint4*)(kr + d);
            float k0 = blo(u.x), k1 = bhi(u.x), k2 = blo(u.y), k3 = bhi(u.y);
            float k4 = blo(u.z), k5 = bhi(u.z), k6 = blo(u.w), k7 = bhi(u.w);
#pragma unroll
            for (int s = 0; s < Ss; ++s)
                acc[s] += qs[s][d + 0] * k0 + qs[s][d + 1] * k1
                        + qs[s][d + 2] * k2 + qs[s][d + 3] * k3
                        + qs[s][d + 4] * k4 + qs[s][d + 5] * k5
                        + qs[s][d + 6] * k6 + qs[s][d + 7] * k7;
        }
#pragma unroll
        for (int s = 0; s < Ss; ++s) sc[s][t] = acc[s];
    }
    __syncthreads();

    const int s    = tid >> 5;
    const int lane = tid & 31;
    float mx = -1e30f;
    for (int t = lane; t < Tt; t += 32) mx = fmaxf(mx, sc[s][t]);
#pragma unroll
    for (int m = 16; m >= 1; m >>= 1) mx = fmaxf(mx, __shfl_xor(mx, m));
    float sum = 0.f;
    for (int t = lane; t < Tt; t += 32) {
        float e = __expf(sc[s][t] - mx);
        sc[s][t] = e;
        sum += e;
    }
#pragma unroll
    for (int m = 16; m >= 1; m >>= 1) sum += __shfl_xor(sum, m);
    const float inv = 1.f / sum;
    __syncthreads();

    const int d0 = (tid & 31) * 4;
    const ushort* vb = kv + ((size_t)(b * Tt)) * KVS + Mm + h * KDd + d0;
    float4 acc = make_float4(0.f, 0.f, 0.f, 0.f);
    for (int t = 0; t < Tt; ++t) {
        const float p = sc[s][t];
        uint2 u = *(const uint2*)(vb + (size_t)t * KVS);
        acc.x = fmaf(p, blo(u.x), acc.x);
        acc.y = fmaf(p, bhi(u.x), acc.y);
        acc.z = fmaf(p, blo(u.y), acc.z);
        acc.w = fmaf(p, bhi(u.y), acc.w);
    }
    float4 o = make_float4(acc.x * inv, acc.y * inv, acc.z * inv, acc.w * inv);
    *(float4*)&att[((size_t)(b * Ss + s)) * Mm + h * KDd + d0] = o;
}

// ---------------------------------------------------------------------------
__global__ __launch_bounds__(256)
void ln_add(const float* __restrict__ a, const float* __restrict__ b,
            const float* __restrict__ g, const float* __restrict__ be,
            float* __restrict__ out)
{
    const int row = blockIdx.x;
    const int tid = threadIdx.x;
    const float* ap = a + (size_t)row * Mm;
    const float* bp = b + (size_t)row * Mm;

    float4 av = *(const float4*)&ap[tid * 4];
    float4 bv = *(const float4*)&bp[tid * 4];
    float x0 = av.x + bv.x, x1 = av.y + bv.y, x2 = av.z + bv.z, x3 = av.w + bv.w;
    float s  = x0 + x1 + x2 + x3;
    float ss = x0 * x0 + x1 * x1 + x2 * x2 + x3 * x3;
#pragma unroll
    for (int m = 32; m >= 1; m >>= 1) {
        s  += __shfl_xor(s, m);
        ss += __shfl_xor(ss, m);
    }
    __shared__ float red[2][4];
    const int wid = tid >> 6;
    if ((tid & 63) == 0) { red[0][wid] = s; red[1][wid] = ss; }
    __syncthreads();
    s  = red[0][0] + red[0][1] + red[0][2] + red[0][3];
    ss = red[1][0] + red[1][1] + red[1][2] + red[1][3];
    const float mu  = s * (1.f / (float)Mm);
    const float var = ss * (1.f / (float)Mm) - mu * mu;
    const float inv = rsqrtf(var + 1e-5f);

    float4 gv = *(const float4*)&g[tid * 4];
    float4 bev = *(const float4*)&be[tid * 4];
    float4 o;
    o.x = (x0 - mu) * inv * gv.x + bev.x;
    o.y = (x1 - mu) * inv * gv.y + bev.y;
    o.z = (x2 - mu) * inv * gv.z + bev.z;
    o.w = (x3 - mu) * inv * gv.w + bev.w;
    *(float4*)&out[(size_t)row * Mm + tid * 4] = o;
}

__global__ __launch_bounds__(256)
void combine_kernel(const float* __restrict__ gm, const float* __restrict__ gi,
                    const float* __restrict__ nextm, const float* __restrict__ memory,
                    const float* __restrict__ ibp, const float* __restrict__ fbp,
                    float* __restrict__ out)
{
    const int idx = blockIdx.x * 256 + threadIdx.x;
    const int m  = idx & (Mm - 1);
    const int bs = idx >> 10;
    const int b  = bs >> 3;
    const float ib = ibp[0], fb = fbp[0];
    const float gmi = gm[(size_t)bs * NGg + m];
    const float gmf = gm[(size_t)bs * NGg + Mm + m];
    const float gii = gi[(size_t)b * NGg + m];
    const float gif = gi[(size_t)b * NGg + Mm + m];
    const float ig = 1.f / (1.f + __expf(-(gmi + gii + ib)));
    const float fg = 1.f / (1.f + __expf(-(gmf + gif + fb)));
    out[idx] = ig * tanhf(nextm[idx]) + fg * memory[idx];
}

// ---------------------------------------------------------------------------
extern "C" void kernel_launch(void* const* d_in, const int* in_sizes, int n_in,
                              void* d_out, int out_size, void* d_ws, size_t ws_size,
                              hipStream_t stream)
{
    const float* inputs = (const float*)d_in[0];
    const float* memory = (const float*)d_in[1];
    const float* Wp  = (const float*)d_in[2];
    const float* bp  = (const float*)d_in[3];
    const float* Wq  = (const float*)d_in[4];
    const float* bq  = (const float*)d_in[5];
    const float* Wk  = (const float*)d_in[6];
    const float* bk  = (const float*)d_in[7];
    const float* Wv  = (const float*)d_in[8];
    const float* bv  = (const float*)d_in[9];
    const float* Wm  = (const float*)d_in[10];
    const float* bm  = (const float*)d_in[11];
    const float* g1  = (const float*)d_in[12];
    const float* be1 = (const float*)d_in[13];
    const float* g2  = (const float*)d_in[14];
    const float* be2 = (const float*)d_in[15];
    const float* rl_w = (const float*)d_in[16];
    const float* rl_W = (const float*)d_in[17];
    const float* rl_b = (const float*)d_in[18];
    const float* gl_W = (const float*)d_in[19];
    const float* gl_b = (const float*)d_in[20];
    const float* ibp  = (const float*)d_in[21];
    const float* fbp  = (const float*)d_in[22];
    float* out = (float*)d_out;

    // allow 128 KiB dynamic LDS for the big MFMA GEMM
    (void)hipFuncSetAttribute(reinterpret_cast<const void*>(&gemm_big<1>),
                              hipFuncAttributeMaxDynamicSharedMemorySize, 131072);

    // ---- workspace layout (float units) ----
    const size_t N_SM = (size_t)Bq * Ss * Mm;     // 524,288
    float* ws = (float*)d_ws;
    float* qbuf   = ws;
    float* attb   = qbuf   + N_SM;
    float* mem1   = attb   + N_SM;
    float* mlp1   = mem1   + N_SM;    // unused slot kept
    float* mlp2   = mlp1   + N_SM;
    float* nextm  = mlp2   + N_SM;
    float* gimean = nextm  + N_SM;
    float* gibuf  = gimean + (size_t)Bq * Mm;
    float* gmbuf  = gibuf  + (size_t)Bq * NGg;
    float* skp    = gmbuf  + (size_t)Bq * Ss * NGg;       // split-K partials (gi)
    const size_t SKP_FLOATS = (size_t)8 * 512 * 1024;
    float* bkvx   = skp + SKP_FLOATS;                     // [3072] fused bias
    float* bz     = bkvx + KVS;                           // [512] zeros
    float* pconst = bz + 512;
    // bf16 constants + small bf16 activations
    ushort* ib16  = (ushort*)pconst;                      // [B*T][DIN]
    ushort* Wp16  = ib16  + (size_t)Bq * Tt * DIN;        // [DIN][M] bf16(Wp)
    ushort* WkvT  = Wp16  + (size_t)DIN * Mm;             // [2M][M]
    ushort* WqT   = WkvT  + (size_t)2 * Mm * Mm;          // [M][M]
    ushort* WmT   = WqT   + (size_t)Mm * Mm;              // [M][M]
    ushort* mem16 = WmT   + (size_t)Mm * Mm;              // [B*S][M]
    ushort* m116  = mem16 + N_SM;                         // bf16(mem1)
    ushort* mlp116= m116  + N_SM;                         // bf16(relu(mlp1))
    ushort* kvxBt = mlp116 + N_SM;                        // [3072][512]: WpkvT|WpT
    ushort* glWT  = kvxBt + (size_t)KVS * DIN;            // [8][2048][1024]
    ushort* tanh16= glWT  + (size_t)Ss * NGg * Mm;        // [B*S][M] bf16(tanh(mem))
    ushort* cend  = tanh16 + N_SM;
    // chunk region start (float*, 16B aligned)
    size_t const_u16 = (size_t)(cend - (ushort*)pconst);
    size_t const_floats = (size_t)(pconst - ws) + (const_u16 + 1) / 2;
    const_floats = (const_floats + 3) & ~(size_t)3;       // 16B align
    float* cstart = ws + const_floats;

    // per-chunk: kvx bf16 (Bc*T*KVS u16 = Bc*T*1536 floats)
    int Bc = Bq;
    while (Bc > 1 &&
           (const_floats + (size_t)Bc * Tt * Mm * 3 / 2) * sizeof(float) > ws_size)
        Bc >>= 1;
    ushort* kvxb16 = (ushort*)cstart;                     // [Bc*T][KVS]

    const dim3 blk(256);

    // ---- precompute bf16 operands + fused weights/bias ----
    conv_bf16<<<dim3((Bq * Tt * DIN) / 1024), blk, 0, stream>>>(inputs, ib16);
    conv_bf16<<<dim3((Bq * Ss * Mm) / 1024), blk, 0, stream>>>(memory, mem16);
    conv_bf16<<<dim3((DIN * Mm) / 1024), blk, 0, stream>>>(Wp, Wp16);
    tanh_bf16<<<dim3((Bq * Ss * Mm) / 1024), blk, 0, stream>>>(memory, tanh16);
    transpose_to_bf16<<<dim3(Mm / 32, Mm / 32), blk, 0, stream>>>(Wk, WkvT, Mm, Mm);
    transpose_to_bf16<<<dim3(Mm / 32, Mm / 32), blk, 0, stream>>>(Wv, WkvT + (size_t)Mm * Mm, Mm, Mm);
    transpose_to_bf16<<<dim3(Mm / 32, Mm / 32), blk, 0, stream>>>(Wq, WqT, Mm, Mm);
    transpose_to_bf16<<<dim3(Mm / 32, Mm / 32), blk, 0, stream>>>(Wm, WmT, Mm, Mm);
    // WpT -> tail of kvxBt (rows 2048..3071)
    transpose_to_bf16<<<dim3(Mm / 32, DIN / 32), blk, 0, stream>>>(
        Wp, kvxBt + (size_t)NGg * DIN, DIN, Mm);
    // glWT[s] = (gl_W[s])^T bf16
    for (int s = 0; s < Ss; ++s)
        transpose_to_bf16<<<dim3(NGg / 32, Mm / 32), blk, 0, stream>>>(
            gl_W + (size_t)s * Mm * NGg, glWT + (size_t)s * NGg * Mm, Mm, NGg);
    fill0<<<dim3(2), blk, 0, stream>>>(bz);

    // WpkvT rows 0..2047 of kvxBt: WpkvT[n][d] = sum_m WkvT[n][m] * Wp16[d][m]
    gemm_sm<1,0><<<dim3(DIN/128, (2*Mm)/128), blk, 0, stream>>>(
        WkvT, Wp16, bz, kvxBt, DIN, Mm);

    // fused bias: bkvx[0..2047] = bp@Wkv + [bk|bv]; bkvx[2048..3071] = bp
    fuse_bias<<<dim3(NGg / 64), blk, 0, stream>>>(bp, Wk, Wv, bk, bv, bkvx);
    copy_vec<<<dim3(Mm / 256), blk, 0, stream>>>(bp, bkvx + NGg);

    // q = memory @ Wq + bq   (128^2 MFMA, fp32 out)
    gemm_sm<0,0><<<dim3(Mm/128, (Bq*Ss)/128), blk, 0, stream>>>(
        mem16, WqT, bq, qbuf, Mm, Mm);

    // ---- chunked: kvx (fused, N=3072, K=512), gi_reduce, attention ----
    for (int c0 = 0; c0 < Bq; c0 += Bc) {
        const int rows = Bc * Tt;

        // kvx = bf16(inputs_c @ [Wpkv | Wp] + bkvx)
        gemm_big<1><<<dim3(KVS/256, rows/256), dim3(512), 131072, stream>>>(
            ib16 + (size_t)c0 * Tt * DIN, kvxBt, bkvx, kvxb16, KVS, DIN);

        // gi_mean_c = mean_t relu(rl_w * x)   (x = kvx cols 2048..3071)
        gi_reduce<<<dim3(Bc * (Mm/256)), blk, 0, stream>>>(
            kvxb16, rl_w, gimean + (size_t)c0 * Mm);

        // attention for this chunk
        attn_kernel<<<dim3(Bc * Hh), blk, 0, stream>>>(
            qbuf + (size_t)c0 * Ss * Mm, kvxb16,
            attb + (size_t)c0 * Ss * Mm);
    }

    // mem1 = LN(memory + att) ; then bf16 copy for the MLP GEMMs
    ln_add<<<dim3(Bq * Ss), blk, 0, stream>>>(memory, attb, g1, be1, mem1);
    conv_bf16<<<dim3((Bq * Ss * Mm) / 1024), blk, 0, stream>>>(mem1, m116);

    // mlp1 = relu(mem1 @ Wm + bm)  -> bf16 ; mlp2 = relu(mlp1 @ Wm + bm) -> fp32
    gemm_sm<1,1><<<dim3(Mm/128, (Bq*Ss)/128), blk, 0, stream>>>(
        m116, WmT, bm, mlp116, Mm, Mm);
    gemm_sm<0,1><<<dim3(Mm/128, (Bq*Ss)/128), blk, 0, stream>>>(
        mlp116, WmT, bm, mlp2, Mm, Mm);

    // next = LN(mem1 + mlp2)
    ln_add<<<dim3(Bq * Ss), blk, 0, stream>>>(mem1, mlp2, g2, be2, nextm);

    // gm = tanh(memory) @ gl_W + gl_b   (bf16 MFMA, per-slot batched)
    gm_mfma<<<dim3(NGg/128, 1, Ss), blk, 0, stream>>>(tanh16, glWT, gl_b, gmbuf);

    // gi = gi_mean @ rl_W + rl_b   (split-K=8, fp32)
    gemm_f32_sk<64,64,16,4,4,8,false><<<dim3(NGg/64, Bq/64, 8), blk, 0, stream>>>(
        gimean, Mm, 0, rl_W, NGg, 0, skp, Bq, NGg, Mm);
    sk_reduce<8,false><<<dim3((Bq*NGg)/1024), blk, 0, stream>>>(
        skp, rl_b, 0, gibuf, NGg, 0, (Bq*NGg)/4, NGg);

    // final gates + output
    combine_kernel<<<dim3((Bq*Ss*Mm)/256), blk, 0, stream>>>(
        gmbuf, gibuf, nextm, memory, ibp, fbp, out);
}

// Round 15
// 474.469 us; speedup vs baseline: 1.0767x; 1.0767x over previous
//
#include <hip/hip_runtime.h>
#include <hip/hip_bf16.h>

// Problem constants
#define Bq   64
#define Tt   512
#define DIN  512
#define Ss   8
#define HSs  128
#define Hh   8
#define Mm   1024
#define KDd  128
#define NGg  2048

typedef __attribute__((ext_vector_type(8))) short bf16x8;
typedef __attribute__((ext_vector_type(4))) float f32x4;

__device__ __forceinline__ ushort f2b(float f) {
    union { float f; unsigned u; } v; v.f = f;
    unsigned r = v.u + 0x7fffu + ((v.u >> 16) & 1u);   // RNE
    return (ushort)(r >> 16);
}
__device__ __forceinline__ float b2f(ushort b) {
    union { unsigned u; float f; } v; v.u = ((unsigned)b) << 16;
    return v.f;
}
__device__ __forceinline__ float blo(unsigned u) {
    union { unsigned u; float f; } v; v.u = u << 16; return v.f;
}
__device__ __forceinline__ float bhi(unsigned u) {
    union { unsigned u; float f; } v; v.u = u & 0xffff0000u; return v.f;
}

#define GLOAD_LDS16(g, l) __builtin_amdgcn_global_load_lds( \
    (const __attribute__((address_space(1))) void*)(g),     \
    (__attribute__((address_space(3))) void*)(l), 16, 0, 0)

#define LGKM0 do { asm volatile("s_waitcnt lgkmcnt(0)" ::: "memory");         \
                   __builtin_amdgcn_sched_barrier(0); } while (0)

// ---------------------------------------------------------------------------
// 256x256 bf16 MFMA GEMM (r12 gray-code schedule — best measured), BK=64,
// 512 threads (8 waves as 2x4), minimal 24 ds_read_b128/wave/tile with the
// incremental read batches overlapped under MFMA clusters.
// T1 bijective XCD swizzle; T2 both-sides XOR swizzle (rule #21).
// Requires rows%256==0, N%256==0, K%64==0, K/64 >= 2.
// ---------------------------------------------------------------------------
template<int OUT_BF16>
__global__ __launch_bounds__(512)
void gemm_big(const ushort* __restrict__ A, const ushort* __restrict__ Bt,
              const float* __restrict__ bias, void* __restrict__ Cout,
              int ldc, int Kdim)
{
    extern __shared__ __align__(16) char lds[];   // 131072 bytes

    const int tid  = threadIdx.x;
    const int wid  = tid >> 6;
    const int lane = tid & 63;
    const int wy   = wid >> 2;
    const int wx   = wid & 3;

    const int gx   = gridDim.x;
    const int nwg  = gx * gridDim.y;
    const int orig = blockIdx.y * gx + blockIdx.x;
    const int q8   = nwg >> 3, r8 = nwg & 7;
    const int xcd  = orig & 7, idx8 = orig >> 3;
    const int swz  = (xcd < r8 ? xcd * (q8 + 1)
                               : r8 * (q8 + 1) + (xcd - r8) * q8) + idx8;
    const int row0 = (swz / gx) * 256;
    const int col0 = (swz % gx) * 256;

    const int NT = Kdim >> 6;

    const int sr = tid >> 3;
    const int sq = (tid & 7) ^ (sr & 7);
    const ushort* Asrc = A  + (size_t)(row0 + sr) * Kdim + sq * 8;
    const ushort* Bsrc = Bt + (size_t)(col0 + sr) * Kdim + sq * 8;
    const int ldsw = wid * 1024;

    auto stage = [&](int isB, int U, int h) {
        const ushort* s = (isB ? Bsrc : Asrc) + (size_t)h * 128 * Kdim
                        + (size_t)U * 64;
        char* d = lds + (isB ? 65536 : 0) + ((((U) & 1) * 2 + h) << 14) + ldsw;
        GLOAD_LDS16(s, d);
        GLOAD_LDS16(s + (size_t)64 * Kdim, d + 8192);
    };
    auto stage_tile = [&](int U) {
        stage(0, U, 0); stage(0, U, 1); stage(1, U, 0); stage(1, U, 1);
    };

    const int l15   = lane & 15;
    const int s0_16 = (((lane >> 4)) ^ (lane & 7)) << 4;
    const int s1_16 = ((4 + (lane >> 4)) ^ (lane & 7)) << 4;
    const int aoff  = wy * 8192 + l15 * 128;
    const int boff  = wx * 4096 + l15 * 128;

    f32x4 acc[4][4][2];
#pragma unroll
    for (int p = 0; p < 4; ++p)
#pragma unroll
        for (int m = 0; m < 4; ++m)
#pragma unroll
            for (int n = 0; n < 2; ++n) acc[p][m][n] = (f32x4){0.f,0.f,0.f,0.f};

#define MFMAQ(P, AH, BH)                                                      \
    {                                                                         \
        __builtin_amdgcn_s_setprio(1);                                        \
        _Pragma("unroll")                                                     \
        for (int kk = 0; kk < 2; ++kk)                                        \
            _Pragma("unroll")                                                 \
            for (int m = 0; m < 4; ++m)                                       \
                _Pragma("unroll")                                             \
                for (int n = 0; n < 2; ++n)                                   \
                    acc[P][m][n] = __builtin_amdgcn_mfma_f32_16x16x32_bf16(   \
                        AH[kk][m], BH[kk][n], acc[P][m][n], 0, 0, 0);         \
        __builtin_amdgcn_s_setprio(0);                                        \
    }

    stage_tile(0);
    stage_tile(1);
    asm volatile("s_waitcnt vmcnt(8)" ::: "memory");
    __builtin_amdgcn_s_barrier();
    asm volatile("" ::: "memory");

    for (int U = 0; U < NT; ++U) {
        const char* Ab = lds + ((U & 1) << 15);
        const char* Bb = lds + 65536 + ((U & 1) << 15);

        bf16x8 a0[2][4], a1[2][4];
        bf16x8 b0[2][2], b1[2][2];

#pragma unroll
        for (int m = 0; m < 4; ++m) {
            a0[0][m] = *(const bf16x8*)(Ab + aoff + s0_16 + m * 2048);
            a0[1][m] = *(const bf16x8*)(Ab + aoff + s1_16 + m * 2048);
        }
#pragma unroll
        for (int n = 0; n < 2; ++n) {
            b0[0][n] = *(const bf16x8*)(Bb + boff + s0_16 + n * 2048);
            b0[1][n] = *(const bf16x8*)(Bb + boff + s1_16 + n * 2048);
        }
        LGKM0;

#pragma unroll
        for (int m = 0; m < 4; ++m) {
            a1[0][m] = *(const bf16x8*)(Ab + 16384 + aoff + s0_16 + m * 2048);
            a1[1][m] = *(const bf16x8*)(Ab + 16384 + aoff + s1_16 + m * 2048);
        }
        MFMAQ(0, a0, b0);
        LGKM0;

#pragma unroll
        for (int n = 0; n < 2; ++n) {
            b1[0][n] = *(const bf16x8*)(Bb + 16384 + boff + s0_16 + n * 2048);
            b1[1][n] = *(const bf16x8*)(Bb + 16384 + boff + s1_16 + n * 2048);
        }
        MFMAQ(1, a1, b0);
        LGKM0;

        __builtin_amdgcn_s_barrier();            // B1
        asm volatile("" ::: "memory");
        if (U + 2 < NT) stage_tile(U + 2);

        MFMAQ(3, a1, b1);
        MFMAQ(2, a0, b1);

        if (U + 2 < NT) asm volatile("s_waitcnt vmcnt(8)" ::: "memory");
        else            asm volatile("s_waitcnt vmcnt(0)" ::: "memory");
        __builtin_amdgcn_s_barrier();            // B2
        asm volatile("" ::: "memory");
    }
#undef MFMAQ

#pragma unroll
    for (int p = 0; p < 4; ++p) {
        const int rb = row0 + (p & 1) * 128 + wy * 64 + (lane >> 4) * 4;
        const int cb = col0 + (p >> 1) * 128 + wx * 32 + (lane & 15);
#pragma unroll
        for (int n = 0; n < 2; ++n) {
            const float bv = bias[cb + n * 16];
#pragma unroll
            for (int m = 0; m < 4; ++m) {
#pragma unroll
                for (int r = 0; r < 4; ++r) {
                    const float v = acc[p][m][n][r] + bv;
                    const size_t off = (size_t)(rb + m * 16 + r) * ldc + cb + n * 16;
                    if (OUT_BF16) ((ushort*)Cout)[off] = f2b(v);
                    else          ((float*)Cout)[off]  = v;
                }
            }
        }
    }
}

// ---------------------------------------------------------------------------
// Small 128x128 bf16 MFMA GEMM: BK=32, 4 waves, 64x64/wave, 16 KB LDS.
// ---------------------------------------------------------------------------
template<int OUT_BF16, int RELU>
__global__ __launch_bounds__(256)
void gemm_sm(const ushort* __restrict__ A, const ushort* __restrict__ Bt,
             const float* __restrict__ bias, void* __restrict__ Cout,
             int ldc, int Kdim)
{
    __shared__ __align__(16) ushort As[128 * 32];   // 8 KB
    __shared__ __align__(16) ushort Bs[128 * 32];   // 8 KB

    const int tid  = threadIdx.x;
    const int w    = tid >> 6;
    const int lane = tid & 63;

    const int gx   = gridDim.x;
    const int nwg  = gx * gridDim.y;
    const int orig = blockIdx.y * gx + blockIdx.x;
    const int q8   = nwg >> 3, r8 = nwg & 7;
    const int xcd  = orig & 7, idx8 = orig >> 3;
    const int swz  = (xcd < r8 ? xcd * (q8 + 1)
                               : r8 * (q8 + 1) + (xcd - r8) * q8) + idx8;
    const int row0 = (swz / gx) * 128;
    const int col0 = (swz % gx) * 128;
    const int wr   = w >> 1, wc = w & 1;

    f32x4 acc[4][4];
#pragma unroll
    for (int i = 0; i < 4; ++i)
#pragma unroll
        for (int j = 0; j < 4; ++j) acc[i][j] = (f32x4){0.f, 0.f, 0.f, 0.f};

    const ushort* Ag = A  + (size_t)(row0 + (tid >> 2)) * Kdim + (tid & 3) * 8;
    const ushort* Bg = Bt + (size_t)(col0 + (tid >> 2)) * Kdim + (tid & 3) * 8;

    for (int k0 = 0; k0 < Kdim; k0 += 32) {
        __syncthreads();
#pragma unroll
        for (int is = 0; is < 2; ++is)
            GLOAD_LDS16(Ag + (size_t)is * 64 * Kdim + k0,
                        (char*)As + (is * 256 + w * 64) * 16);
#pragma unroll
        for (int is = 0; is < 2; ++is)
            GLOAD_LDS16(Bg + (size_t)is * 64 * Kdim + k0,
                        (char*)Bs + (is * 256 + w * 64) * 16);
        asm volatile("s_waitcnt vmcnt(0)" ::: "memory");
        __syncthreads();

        bf16x8 a[4], b[4];
#pragma unroll
        for (int i = 0; i < 4; ++i) {
            a[i] = *(const bf16x8*)&As[(wr * 64 + i * 16 + (lane & 15)) * 32 + (lane >> 4) * 8];
            b[i] = *(const bf16x8*)&Bs[(wc * 64 + i * 16 + (lane & 15)) * 32 + (lane >> 4) * 8];
        }
#pragma unroll
        for (int i = 0; i < 4; ++i)
#pragma unroll
            for (int j = 0; j < 4; ++j)
                acc[i][j] = __builtin_amdgcn_mfma_f32_16x16x32_bf16(a[i], b[j], acc[i][j], 0, 0, 0);
    }

    float bsv[4];
#pragma unroll
    for (int j = 0; j < 4; ++j) bsv[j] = bias[col0 + wc * 64 + j * 16 + (lane & 15)];
#pragma unroll
    for (int i = 0; i < 4; ++i) {
        const int row = row0 + wr * 64 + i * 16 + (lane >> 4) * 4;
        const int col = col0 + wc * 64 + (lane & 15);
#pragma unroll
        for (int r = 0; r < 4; ++r) {
            const size_t off = (size_t)(row + r) * ldc + col;
#pragma unroll
            for (int j = 0; j < 4; ++j) {
                float vv = acc[i][j][r] + bsv[j];
                if (RELU) vv = fmaxf(vv, 0.f);
                if (OUT_BF16) ((ushort*)Cout)[off + j * 16] = f2b(vv);
                else          ((float*)Cout)[off + j * 16]  = vv;
            }
        }
    }
}

// ---------------------------------------------------------------------------
// gm_direct: gm[b][s][n] = tanh16[b][s][:] @ gl_W[s][:][n] + gl_b[s][n]
// No LDS, no transposes: B fragments built in-register from fp32 gl_W reads
// (col-coalesced 64B segments), A fragments from bf16 tanh16 via L1.
// Grid (NGg/64, Ss) = 256 blocks x 256 thr (4 waves, BN=16 per wave).
// B-frag layout: col = lane&15, k = (lane>>4)*8 + j. A-frag: row = lane&15.
// ---------------------------------------------------------------------------
__global__ __launch_bounds__(256)
void gm_direct(const ushort* __restrict__ tanhA, const float* __restrict__ glW,
               const float* __restrict__ gl_b, float* __restrict__ gm)
{
    const int tid  = threadIdx.x;
    const int w    = tid >> 6;
    const int lane = tid & 63;
    const int s    = blockIdx.y;
    const int n    = blockIdx.x * 64 + w * 16 + (lane & 15);
    const int q8   = (lane >> 4) * 8;

    const float* Bp = glW + (size_t)s * Mm * NGg + n;   // column n, row k stride NGg

    f32x4 acc[4];
#pragma unroll
    for (int i = 0; i < 4; ++i) acc[i] = (f32x4){0.f, 0.f, 0.f, 0.f};

#pragma unroll 2
    for (int k0 = 0; k0 < Mm; k0 += 32) {
        bf16x8 a[4];
#pragma unroll
        for (int i = 0; i < 4; ++i)
            a[i] = *(const bf16x8*)&tanhA[((size_t)(i * 16 + (lane & 15)) * Ss + s) * Mm + k0 + q8];
        bf16x8 bv;
#pragma unroll
        for (int j = 0; j < 8; ++j)
            bv[j] = (short)f2b(Bp[(size_t)(k0 + q8 + j) * NGg]);
#pragma unroll
        for (int i = 0; i < 4; ++i)
            acc[i] = __builtin_amdgcn_mfma_f32_16x16x32_bf16(a[i], bv, acc[i], 0, 0, 0);
    }

    const float bb = gl_b[s * NGg + n];
#pragma unroll
    for (int i = 0; i < 4; ++i) {
#pragma unroll
        for (int r = 0; r < 4; ++r) {
            const int b = i * 16 + (lane >> 4) * 4 + r;
            gm[((size_t)b * Ss + s) * NGg + n] = acc[i][r] + bb;
        }
    }
}

// ---------------------------------------------------------------------------
// transpose + convert: out[C][R] bf16 = in[R][C] fp32   (R,C multiples of 32)
// ---------------------------------------------------------------------------
__global__ __launch_bounds__(256)
void transpose_to_bf16(const float* __restrict__ in, ushort* __restrict__ out,
                       int R, int C)
{
    __shared__ float t[32][33];
    const int c0 = blockIdx.x * 32, r0 = blockIdx.y * 32;
    const int tx = threadIdx.x & 31, ty = threadIdx.x >> 5;   // 32 x 8
#pragma unroll
    for (int i = 0; i < 32; i += 8)
        t[ty + i][tx] = in[(size_t)(r0 + ty + i) * C + c0 + tx];
    __syncthreads();
#pragma unroll
    for (int i = 0; i < 32; i += 8)
        out[(size_t)(c0 + ty + i) * R + r0 + tx] = f2b(t[tx][ty + i]);
}

// elementwise fp32 -> bf16 (n divisible by 1024)
__global__ __launch_bounds__(256)
void conv_bf16(const float* __restrict__ in, ushort* __restrict__ out)
{
    const int i = blockIdx.x * 256 + threadIdx.x;
    float4 v = ((const float4*)in)[i];
    ushort4 o;
    o.x = f2b(v.x); o.y = f2b(v.y); o.z = f2b(v.z); o.w = f2b(v.w);
    ((ushort4*)out)[i] = o;
}

// elementwise tanh(fp32) -> bf16 (n divisible by 1024)
__global__ __launch_bounds__(256)
void tanh_bf16(const float* __restrict__ in, ushort* __restrict__ out)
{
    const int i = blockIdx.x * 256 + threadIdx.x;
    float4 v = ((const float4*)in)[i];
    ushort4 o;
    o.x = f2b(tanhf(v.x)); o.y = f2b(tanhf(v.y));
    o.z = f2b(tanhf(v.z)); o.w = f2b(tanhf(v.w));
    ((ushort4*)out)[i] = o;
}

// zero-fill n floats (n divisible by 256)
__global__ __launch_bounds__(256)
void fill0(float* __restrict__ o)
{
    o[blockIdx.x * 256 + threadIdx.x] = 0.f;
}

// ---------------------------------------------------------------------------
// fuse_bias: outb[n] = sum_m bp[m] * Wkv[m][n] + bkv[n], n in [0, 2048).
// ---------------------------------------------------------------------------
__global__ __launch_bounds__(256)
void fuse_bias(const float* __restrict__ bp,
               const float* __restrict__ Wk, const float* __restrict__ Wv,
               const float* __restrict__ bk, const float* __restrict__ bv,
               float* __restrict__ outb)
{
    __shared__ float red[4][64];
    const int col = threadIdx.x & 63;
    const int mq  = threadIdx.x >> 6;
    const int n   = blockIdx.x * 64 + col;
    const float* W = (n < Mm) ? Wk : Wv;
    const int nn   = n & (Mm - 1);
    float s = 0.f;
    for (int m = mq * 256; m < mq * 256 + 256; ++m)
        s += bp[m] * W[(size_t)m * Mm + nn];
    red[mq][col] = s;
    __syncthreads();
    if (mq == 0) {
        float t = red[0][col] + red[1][col] + red[2][col] + red[3][col];
        outb[n] = t + ((n < Mm) ? bk[nn] : bv[nn]);
    }
}

// ---------------------------------------------------------------------------
// Split-K fp32 GEMM: partials P[zz][Mrows][Ncols], zz = batch*SPLITK + ks.
// ---------------------------------------------------------------------------
template<int BM, int BN, int BK, int TM, int TN, int SPLITK>
__global__ __launch_bounds__(256)
void gemm_f32_sk(const float* __restrict__ A, int lda, long long sA,
                 const float* __restrict__ B, int ldb, long long sB,
                 float* __restrict__ P, int Mrows, int Ncols, int Kdim)
{
    constexpr int TX = BN / TN;
    constexpr int TY = BM / TM;
    static_assert(TX * TY == 256, "256 threads");
    constexpr int KC4   = BK / 4;
    constexpr int A_PER = (BM * BK / 4) / 256;
    constexpr int B_PER = (BK * BN / 4) / 256;

    __shared__ float As[BK][BM + 4];
    __shared__ float Bs[BK][BN];

    const int tid = threadIdx.x;
    const int tx  = tid % TX;
    const int ty  = tid / TX;
    const int zz  = blockIdx.z;
    const int zb  = zz / SPLITK;
    const int ks  = zz % SPLITK;
    A += (long long)zb * sA;
    B += (long long)zb * sB;
    const int Kslice = Kdim / SPLITK;
    const int kbeg = ks * Kslice, kend = kbeg + Kslice;
    const int row0 = blockIdx.y * BM;
    const int col0 = blockIdx.x * BN;

    float acc[TM][TN];
#pragma unroll
    for (int i = 0; i < TM; ++i)
#pragma unroll
        for (int j = 0; j < TN; ++j) acc[i][j] = 0.f;

    for (int k0 = kbeg; k0 < kend; k0 += BK) {
        __syncthreads();
#pragma unroll
        for (int l = 0; l < A_PER; ++l) {
            int idx = tid + l * 256;
            int ar  = idx / KC4;
            int ac  = (idx % KC4) * 4;
            float4 va = *(const float4*)&A[(long long)(row0 + ar) * lda + k0 + ac];
            As[ac + 0][ar] = va.x;
            As[ac + 1][ar] = va.y;
            As[ac + 2][ar] = va.z;
            As[ac + 3][ar] = va.w;
        }
#pragma unroll
        for (int l = 0; l < B_PER; ++l) {
            int idx = tid + l * 256;
            int br  = idx / (BN / 4);
            int bc  = (idx % (BN / 4)) * 4;
            *(float4*)&Bs[br][bc] = *(const float4*)&B[(long long)(k0 + br) * ldb + col0 + bc];
        }
        __syncthreads();
#pragma unroll
        for (int k = 0; k < BK; ++k) {
            float a[TM], b[TN];
#pragma unroll
            for (int i = 0; i < TM; i += 4)
                *(float4*)&a[i] = *(const float4*)&As[k][ty * TM + i];
#pragma unroll
            for (int j = 0; j < TN; j += 4)
                *(float4*)&b[j] = *(const float4*)&Bs[k][tx * TN + j];
#pragma unroll
            for (int i = 0; i < TM; ++i)
#pragma unroll
                for (int j = 0; j < TN; ++j)
                    acc[i][j] = fmaf(a[i], b[j], acc[i][j]);
        }
    }

    float* Pz = P + (size_t)zz * Mrows * Ncols;
#pragma unroll
    for (int i = 0; i < TM; ++i) {
        const size_t prow = (size_t)(row0 + ty * TM + i) * Ncols;
#pragma unroll
        for (int j = 0; j < TN; j += 4)
            *(float4*)&Pz[prow + col0 + tx * TN + j] = *(const float4*)&acc[i][j];
    }
}

// ---------------------------------------------------------------------------
// sk_reduce: C[batch][row][col] = (relu?)( sum_ks P + bias[batch][col] )
// ---------------------------------------------------------------------------
template<int SPLITK, bool RELU>
__global__ __launch_bounds__(256)
void sk_reduce(const float* __restrict__ P, const float* __restrict__ bias,
               long long sBias, float* __restrict__ C, int ldc, long long sC,
               int pb4, int Ncols)
{
    const int gid = blockIdx.x * 256 + threadIdx.x;
    const int batch = gid / pb4;
    const int r4    = gid % pb4;
    const float4* Pb = (const float4*)P + (size_t)batch * SPLITK * pb4 + r4;
    float4 s = Pb[0];
#pragma unroll
    for (int ks = 1; ks < SPLITK; ++ks) {
        float4 p = Pb[(size_t)ks * pb4];
        s.x += p.x; s.y += p.y; s.z += p.z; s.w += p.w;
    }
    const int col = (r4 * 4) % Ncols;
    const int row = (r4 * 4) / Ncols;
    float4 bv = *(const float4*)&bias[batch * sBias + col];
    s.x += bv.x; s.y += bv.y; s.z += bv.z; s.w += bv.w;
    if (RELU) {
        s.x = fmaxf(s.x, 0.f); s.y = fmaxf(s.y, 0.f);
        s.z = fmaxf(s.z, 0.f); s.w = fmaxf(s.w, 0.f);
    }
    *(float4*)&C[(size_t)batch * sC + (size_t)row * ldc + col] = s;
}

// ---------------------------------------------------------------------------
// gi_mean[b, m] = (1/T) * sum_t relu(rl_w[m] * x_bf16[b, t, m])
// ---------------------------------------------------------------------------
__global__ __launch_bounds__(256)
void gi_reduce(const ushort* __restrict__ x, const float* __restrict__ rl_w,
               float* __restrict__ gi_mean)
{
    const int b    = blockIdx.x / (Mm / 256);
    const int mblk = blockIdx.x % (Mm / 256);
    const int m    = mblk * 256 + threadIdx.x;
    const float w  = rl_w[m];
    const ushort* xp = x + (size_t)b * Tt * Mm + m;
    float sum = 0.f;
    for (int t = 0; t < Tt; ++t)
        sum += fmaxf(w * b2f(xp[(size_t)t * Mm]), 0.f);
    gi_mean[b * Mm + m] = sum * (1.f / (float)Tt);
}

// ---------------------------------------------------------------------------
// Fused attention per (b, h): q fp32 [.,S,M]; kv bf16 [.,T,2M]
// ---------------------------------------------------------------------------
__global__ __launch_bounds__(256)
void attn_kernel(const float* __restrict__ q, const ushort* __restrict__ kv,
                 float* __restrict__ att)
{
    const int b = blockIdx.x / Hh;
    const int h = blockIdx.x % Hh;
    const int tid = threadIdx.x;

    __shared__ float qs[Ss][KDd];
    __shared__ float sc[Ss][Tt];

    {
        int s  = tid / 32;
        int d4 = (tid % 32) * 4;
        float4 qv = *(const float4*)&q[((size_t)(b * Ss + s)) * Mm + h * KDd + d4];
        qs[s][d4 + 0] = qv.x; qs[s][d4 + 1] = qv.y;
        qs[s][d4 + 2] = qv.z; qs[s][d4 + 3] = qv.w;
    }
    __syncthreads();

#pragma unroll
    for (int half = 0; half < 2; ++half) {
        const int t = tid + half * 256;
        const ushort* kr = kv + ((size_t)(b * Tt + t)) * (2 * Mm) + h * KDd;
        float acc[Ss];
#pragma unroll
        for (int s = 0; s < Ss; ++s) acc[s] = 0.f;
        for (int d = 0; d < KDd; d += 8) {
            uint4 u = *(const uint4*)(kr + d);
            float k0 = blo(u.x), k1 = bhi(u.x), k2 = blo(u.y), k3 = bhi(u.y);
            float k4 = blo(u.z), k5 = bhi(u.z), k6 = blo(u.w), k7 = bhi(u.w);
#pragma unroll
            for (int s = 0; s < Ss; ++s)
                acc[s] += qs[s][d + 0] * k0 + qs[s][d + 1] * k1
                        + qs[s][d + 2] * k2 + qs[s][d + 3] * k3
                        + qs[s][d + 4] * k4 + qs[s][d + 5] * k5
                        + qs[s][d + 6] * k6 + qs[s][d + 7] * k7;
        }
#pragma unroll
        for (int s = 0; s < Ss; ++s) sc[s][t] = acc[s];
    }
    __syncthreads();

    const int s    = tid >> 5;
    const int lane = tid & 31;
    float mx = -1e30f;
    for (int t = lane; t < Tt; t += 32) mx = fmaxf(mx, sc[s][t]);
#pragma unroll
    for (int m = 16; m >= 1; m >>= 1) mx = fmaxf(mx, __shfl_xor(mx, m));
    float sum = 0.f;
    for (int t = lane; t < Tt; t += 32) {
        float e = __expf(sc[s][t] - mx);
        sc[s][t] = e;
        sum += e;
    }
#pragma unroll
    for (int m = 16; m >= 1; m >>= 1) sum += __shfl_xor(sum, m);
    const float inv = 1.f / sum;
    __syncthreads();

    const int d0 = (tid & 31) * 4;
    const ushort* vb = kv + ((size_t)(b * Tt)) * (2 * Mm) + Mm + h * KDd + d0;
    float4 acc = make_float4(0.f, 0.f, 0.f, 0.f);
    for (int t = 0; t < Tt; ++t) {
        const float p = sc[s][t];
        uint2 u = *(const uint2*)(vb + (size_t)t * (2 * Mm));
        acc.x = fmaf(p, blo(u.x), acc.x);
        acc.y = fmaf(p, bhi(u.x), acc.y);
        acc.z = fmaf(p, blo(u.y), acc.z);
        acc.w = fmaf(p, bhi(u.y), acc.w);
    }
    float4 o = make_float4(acc.x * inv, acc.y * inv, acc.z * inv, acc.w * inv);
    *(float4*)&att[((size_t)(b * Ss + s)) * Mm + h * KDd + d0] = o;
}

// ---------------------------------------------------------------------------
__global__ __launch_bounds__(256)
void ln_add(const float* __restrict__ a, const float* __restrict__ b,
            const float* __restrict__ g, const float* __restrict__ be,
            float* __restrict__ out)
{
    const int row = blockIdx.x;
    const int tid = threadIdx.x;
    const float* ap = a + (size_t)row * Mm;
    const float* bp = b + (size_t)row * Mm;

    float4 av = *(const float4*)&ap[tid * 4];
    float4 bv = *(const float4*)&bp[tid * 4];
    float x0 = av.x + bv.x, x1 = av.y + bv.y, x2 = av.z + bv.z, x3 = av.w + bv.w;
    float s  = x0 + x1 + x2 + x3;
    float ss = x0 * x0 + x1 * x1 + x2 * x2 + x3 * x3;
#pragma unroll
    for (int m = 32; m >= 1; m >>= 1) {
        s  += __shfl_xor(s, m);
        ss += __shfl_xor(ss, m);
    }
    __shared__ float red[2][4];
    const int wid = tid >> 6;
    if ((tid & 63) == 0) { red[0][wid] = s; red[1][wid] = ss; }
    __syncthreads();
    s  = red[0][0] + red[0][1] + red[0][2] + red[0][3];
    ss = red[1][0] + red[1][1] + red[1][2] + red[1][3];
    const float mu  = s * (1.f / (float)Mm);
    const float var = ss * (1.f / (float)Mm) - mu * mu;
    const float inv = rsqrtf(var + 1e-5f);

    float4 gv = *(const float4*)&g[tid * 4];
    float4 bev = *(const float4*)&be[tid * 4];
    float4 o;
    o.x = (x0 - mu) * inv * gv.x + bev.x;
    o.y = (x1 - mu) * inv * gv.y + bev.y;
    o.z = (x2 - mu) * inv * gv.z + bev.z;
    o.w = (x3 - mu) * inv * gv.w + bev.w;
    *(float4*)&out[(size_t)row * Mm + tid * 4] = o;
}

__global__ __launch_bounds__(256)
void combine_kernel(const float* __restrict__ gm, const float* __restrict__ gi,
                    const float* __restrict__ nextm, const float* __restrict__ memory,
                    const float* __restrict__ ibp, const float* __restrict__ fbp,
                    float* __restrict__ out)
{
    const int idx = blockIdx.x * 256 + threadIdx.x;
    const int m  = idx & (Mm - 1);
    const int bs = idx >> 10;
    const int b  = bs >> 3;
    const float ib = ibp[0], fb = fbp[0];
    const float gmi = gm[(size_t)bs * NGg + m];
    const float gmf = gm[(size_t)bs * NGg + Mm + m];
    const float gii = gi[(size_t)b * NGg + m];
    const float gif = gi[(size_t)b * NGg + Mm + m];
    const float ig = 1.f / (1.f + __expf(-(gmi + gii + ib)));
    const float fg = 1.f / (1.f + __expf(-(gmf + gif + fb)));
    out[idx] = ig * tanhf(nextm[idx]) + fg * memory[idx];
}

// ---------------------------------------------------------------------------
extern "C" void kernel_launch(void* const* d_in, const int* in_sizes, int n_in,
                              void* d_out, int out_size, void* d_ws, size_t ws_size,
                              hipStream_t stream)
{
    const float* inputs = (const float*)d_in[0];
    const float* memory = (const float*)d_in[1];
    const float* Wp  = (const float*)d_in[2];
    const float* bp  = (const float*)d_in[3];
    const float* Wq  = (const float*)d_in[4];
    const float* bq  = (const float*)d_in[5];
    const float* Wk  = (const float*)d_in[6];
    const float* bk  = (const float*)d_in[7];
    const float* Wv  = (const float*)d_in[8];
    const float* bv  = (const float*)d_in[9];
    const float* Wm  = (const float*)d_in[10];
    const float* bm  = (const float*)d_in[11];
    const float* g1  = (const float*)d_in[12];
    const float* be1 = (const float*)d_in[13];
    const float* g2  = (const float*)d_in[14];
    const float* be2 = (const float*)d_in[15];
    const float* rl_w = (const float*)d_in[16];
    const float* rl_W = (const float*)d_in[17];
    const float* rl_b = (const float*)d_in[18];
    const float* gl_W = (const float*)d_in[19];
    const float* gl_b = (const float*)d_in[20];
    const float* ibp  = (const float*)d_in[21];
    const float* fbp  = (const float*)d_in[22];
    float* out = (float*)d_out;

    // allow 128 KiB dynamic LDS for the big MFMA GEMM
    (void)hipFuncSetAttribute(reinterpret_cast<const void*>(&gemm_big<1>),
                              hipFuncAttributeMaxDynamicSharedMemorySize, 131072);

    // ---- workspace layout (float units) ----
    const size_t N_SM = (size_t)Bq * Ss * Mm;     // 524,288
    float* ws = (float*)d_ws;
    float* qbuf   = ws;
    float* attb   = qbuf   + N_SM;
    float* mem1   = attb   + N_SM;
    float* mlp1   = mem1   + N_SM;    // unused slot kept
    float* mlp2   = mlp1   + N_SM;
    float* nextm  = mlp2   + N_SM;
    float* gimean = nextm  + N_SM;
    float* gibuf  = gimean + (size_t)Bq * Mm;
    float* gmbuf  = gibuf  + (size_t)Bq * NGg;
    float* skp    = gmbuf  + (size_t)Bq * Ss * NGg;       // split-K partials (gi)
    const size_t SKP_FLOATS = (size_t)8 * 512 * 1024;
    float* bkvf   = skp + SKP_FLOATS;                     // [2048] fused bias
    float* bz     = bkvf + NGg;                           // [512] zeros
    float* pconst = bz + 512;
    // bf16 constants + small bf16 activations
    ushort* ib16  = (ushort*)pconst;                      // [B*T][DIN]
    ushort* WpT   = ib16  + (size_t)Bq * Tt * DIN;        // [M][DIN]
    ushort* WkvT  = WpT   + (size_t)Mm * DIN;             // [2M][M]
    ushort* WqT   = WkvT  + (size_t)2 * Mm * Mm;          // [M][M]
    ushort* WmT   = WqT   + (size_t)Mm * Mm;              // [M][M]
    ushort* mem16 = WmT   + (size_t)Mm * Mm;              // [B*S][M]
    ushort* m116  = mem16 + N_SM;                         // bf16(mem1)
    ushort* mlp116= m116  + N_SM;                         // bf16(relu(mlp1))
    ushort* Wp16  = mlp116 + N_SM;                        // [DIN][M] bf16(Wp)
    ushort* WpkvT = Wp16  + (size_t)DIN * Mm;             // [2M][DIN] bf16(Wp@Wkv)^T
    ushort* tanh16= WpkvT + (size_t)2 * Mm * DIN;         // [B*S][M] bf16(tanh(mem))
    ushort* cend  = tanh16 + N_SM;
    // chunk region start (float*, 16B aligned)
    size_t const_u16 = (size_t)(cend - (ushort*)pconst);
    size_t const_floats = (size_t)(pconst - ws) + (const_u16 + 1) / 2;
    const_floats = (const_floats + 3) & ~(size_t)3;       // 16B align
    float* cstart = ws + const_floats;

    // per-chunk: kv bf16 (Bc*T*2M u16) + xb16 (Bc*T*M u16)
    int Bc = Bq;
    while (Bc > 1 &&
           (const_floats + (size_t)Bc * Tt * Mm * 3 / 2) * sizeof(float) > ws_size)
        Bc >>= 1;
    const size_t N_XC = (size_t)Bc * Tt * Mm;
    ushort* kvb16 = (ushort*)cstart;                      // [Bc*T][2M]
    ushort* xb16  = kvb16 + 2 * N_XC;                     // [Bc*T][M]

    const dim3 blk(256);

    // ---- precompute bf16 operands + fused weights/bias ----
    conv_bf16<<<dim3((Bq * Tt * DIN) / 1024), blk, 0, stream>>>(inputs, ib16);
    conv_bf16<<<dim3((Bq * Ss * Mm) / 1024), blk, 0, stream>>>(memory, mem16);
    conv_bf16<<<dim3((DIN * Mm) / 1024), blk, 0, stream>>>(Wp, Wp16);
    tanh_bf16<<<dim3((Bq * Ss * Mm) / 1024), blk, 0, stream>>>(memory, tanh16);
    transpose_to_bf16<<<dim3(Mm / 32, DIN / 32), blk, 0, stream>>>(Wp, WpT, DIN, Mm);
    transpose_to_bf16<<<dim3(Mm / 32, Mm / 32), blk, 0, stream>>>(Wk, WkvT, Mm, Mm);
    transpose_to_bf16<<<dim3(Mm / 32, Mm / 32), blk, 0, stream>>>(Wv, WkvT + (size_t)Mm * Mm, Mm, Mm);
    transpose_to_bf16<<<dim3(Mm / 32, Mm / 32), blk, 0, stream>>>(Wq, WqT, Mm, Mm);
    transpose_to_bf16<<<dim3(Mm / 32, Mm / 32), blk, 0, stream>>>(Wm, WmT, Mm, Mm);
    fill0<<<dim3(2), blk, 0, stream>>>(bz);

    // WpkvT[n][d] = sum_m WkvT[n][m] * Wp16[d][m]  (= (Wp@Wkv)^T, bf16)
    gemm_sm<1,0><<<dim3(DIN/128, (2*Mm)/128), blk, 0, stream>>>(
        WkvT, Wp16, bz, WpkvT, DIN, Mm);

    // bkvf[n] = bp @ Wkv[:,n] + [bk|bv][n]   (fp32, deterministic)
    fuse_bias<<<dim3(NGg / 64), blk, 0, stream>>>(bp, Wk, Wv, bk, bv, bkvf);

    // q = memory @ Wq + bq   (128^2 MFMA, fp32 out)
    gemm_sm<0,0><<<dim3(Mm/128, (Bq*Ss)/128), blk, 0, stream>>>(
        mem16, WqT, bq, qbuf, Mm, Mm);

    // ---- chunked: kv (fused, K=512), x (for gi), gi_reduce, attention ----
    for (int c0 = 0; c0 < Bq; c0 += Bc) {
        const int rows = Bc * Tt;

        // kv = bf16(inputs_c @ Wpkv + bkvf)   (N=2048, K=512)
        gemm_big<1><<<dim3((2*Mm)/256, rows/256), dim3(512), 131072, stream>>>(
            ib16 + (size_t)c0 * Tt * DIN, WpkvT, bkvf, kvb16, 2*Mm, DIN);

        // x_bf16 = bf16(inputs_c @ Wp + bp)   (only needed for gi_mean)
        gemm_big<1><<<dim3(Mm/256, rows/256), dim3(512), 131072, stream>>>(
            ib16 + (size_t)c0 * Tt * DIN, WpT, bp, xb16, Mm, DIN);

        // gi_mean_c = mean_t relu(rl_w * x)
        gi_reduce<<<dim3(Bc * (Mm/256)), blk, 0, stream>>>(
            xb16, rl_w, gimean + (size_t)c0 * Mm);

        // attention for this chunk
        attn_kernel<<<dim3(Bc * Hh), blk, 0, stream>>>(
            qbuf + (size_t)c0 * Ss * Mm, kvb16,
            attb + (size_t)c0 * Ss * Mm);
    }

    // mem1 = LN(memory + att) ; then bf16 copy for the MLP GEMMs
    ln_add<<<dim3(Bq * Ss), blk, 0, stream>>>(memory, attb, g1, be1, mem1);
    conv_bf16<<<dim3((Bq * Ss * Mm) / 1024), blk, 0, stream>>>(mem1, m116);

    // mlp1 = relu(mem1 @ Wm + bm)  -> bf16 ; mlp2 = relu(mlp1 @ Wm + bm) -> fp32
    gemm_sm<1,1><<<dim3(Mm/128, (Bq*Ss)/128), blk, 0, stream>>>(
        m116, WmT, bm, mlp116, Mm, Mm);
    gemm_sm<0,1><<<dim3(Mm/128, (Bq*Ss)/128), blk, 0, stream>>>(
        mlp116, WmT, bm, mlp2, Mm, Mm);

    // next = LN(mem1 + mlp2)
    ln_add<<<dim3(Bq * Ss), blk, 0, stream>>>(mem1, mlp2, g2, be2, nextm);

    // gm = tanh(memory) @ gl_W + gl_b   (direct bf16 MFMA, no transposes)
    gm_direct<<<dim3(NGg / 64, Ss), blk, 0, stream>>>(tanh16, gl_W, gl_b, gmbuf);

    // gi = gi_mean @ rl_W + rl_b   (split-K=8, fp32)
    gemm_f32_sk<64,64,16,4,4,8><<<dim3(NGg/64, Bq/64, 8), blk, 0, stream>>>(
        gimean, Mm, 0, rl_W, NGg, 0, skp, Bq, NGg, Mm);
    sk_reduce<8,false><<<dim3((Bq*NGg)/1024), blk, 0, stream>>>(
        skp, rl_b, 0, gibuf, NGg, 0, (Bq*NGg)/4, NGg);

    // final gates + output
    combine_kernel<<<dim3((Bq*Ss*Mm)/256), blk, 0, stream>>>(
        gmbuf, gibuf, nextm, memory, ibp, fbp, out);
}

// Round 16
// 463.950 us; speedup vs baseline: 1.1012x; 1.0227x over previous
//
#include <hip/hip_runtime.h>
#include <hip/hip_bf16.h>

// Problem constants
#define Bq   64
#define Tt   512
#define DIN  512
#define Ss   8
#define HSs  128
#define Hh   8
#define Mm   1024
#define KDd  128
#define NGg  2048

typedef __attribute__((ext_vector_type(8))) short bf16x8;
typedef __attribute__((ext_vector_type(4))) float f32x4;

__device__ __forceinline__ ushort f2b(float f) {
    union { float f; unsigned u; } v; v.f = f;
    unsigned r = v.u + 0x7fffu + ((v.u >> 16) & 1u);   // RNE
    return (ushort)(r >> 16);
}
__device__ __forceinline__ float b2f(ushort b) {
    union { unsigned u; float f; } v; v.u = ((unsigned)b) << 16;
    return v.f;
}
__device__ __forceinline__ float blo(unsigned u) {
    union { unsigned u; float f; } v; v.u = u << 16; return v.f;
}
__device__ __forceinline__ float bhi(unsigned u) {
    union { unsigned u; float f; } v; v.u = u & 0xffff0000u; return v.f;
}

#define GLOAD_LDS16(g, l) __builtin_amdgcn_global_load_lds( \
    (const __attribute__((address_space(1))) void*)(g),     \
    (__attribute__((address_space(3))) void*)(l), 16, 0, 0)

#define LGKM0 do { asm volatile("s_waitcnt lgkmcnt(0)" ::: "memory");         \
                   __builtin_amdgcn_sched_barrier(0); } while (0)

// ---------------------------------------------------------------------------
// 256x256 bf16 MFMA GEMM (r12 gray-code schedule — best measured), BK=64,
// 512 threads (8 waves as 2x4), minimal 24 ds_read_b128/wave/tile with the
// incremental read batches overlapped under MFMA clusters.
// T1 bijective XCD swizzle; T2 both-sides XOR swizzle (rule #21).
// Requires rows%256==0, N%256==0, K%64==0, K/64 >= 2.
// ---------------------------------------------------------------------------
template<int OUT_BF16>
__global__ __launch_bounds__(512)
void gemm_big(const ushort* __restrict__ A, const ushort* __restrict__ Bt,
              const float* __restrict__ bias, void* __restrict__ Cout,
              int ldc, int Kdim)
{
    extern __shared__ __align__(16) char lds[];   // 131072 bytes

    const int tid  = threadIdx.x;
    const int wid  = tid >> 6;
    const int lane = tid & 63;
    const int wy   = wid >> 2;
    const int wx   = wid & 3;

    const int gx   = gridDim.x;
    const int nwg  = gx * gridDim.y;
    const int orig = blockIdx.y * gx + blockIdx.x;
    const int q8   = nwg >> 3, r8 = nwg & 7;
    const int xcd  = orig & 7, idx8 = orig >> 3;
    const int swz  = (xcd < r8 ? xcd * (q8 + 1)
                               : r8 * (q8 + 1) + (xcd - r8) * q8) + idx8;
    const int row0 = (swz / gx) * 256;
    const int col0 = (swz % gx) * 256;

    const int NT = Kdim >> 6;

    const int sr = tid >> 3;
    const int sq = (tid & 7) ^ (sr & 7);
    const ushort* Asrc = A  + (size_t)(row0 + sr) * Kdim + sq * 8;
    const ushort* Bsrc = Bt + (size_t)(col0 + sr) * Kdim + sq * 8;
    const int ldsw = wid * 1024;

    auto stage = [&](int isB, int U, int h) {
        const ushort* s = (isB ? Bsrc : Asrc) + (size_t)h * 128 * Kdim
                        + (size_t)U * 64;
        char* d = lds + (isB ? 65536 : 0) + ((((U) & 1) * 2 + h) << 14) + ldsw;
        GLOAD_LDS16(s, d);
        GLOAD_LDS16(s + (size_t)64 * Kdim, d + 8192);
    };
    auto stage_tile = [&](int U) {
        stage(0, U, 0); stage(0, U, 1); stage(1, U, 0); stage(1, U, 1);
    };

    const int l15   = lane & 15;
    const int s0_16 = (((lane >> 4)) ^ (lane & 7)) << 4;
    const int s1_16 = ((4 + (lane >> 4)) ^ (lane & 7)) << 4;
    const int aoff  = wy * 8192 + l15 * 128;
    const int boff  = wx * 4096 + l15 * 128;

    f32x4 acc[4][4][2];
#pragma unroll
    for (int p = 0; p < 4; ++p)
#pragma unroll
        for (int m = 0; m < 4; ++m)
#pragma unroll
            for (int n = 0; n < 2; ++n) acc[p][m][n] = (f32x4){0.f,0.f,0.f,0.f};

#define MFMAQ(P, AH, BH)                                                      \
    {                                                                         \
        __builtin_amdgcn_s_setprio(1);                                        \
        _Pragma("unroll")                                                     \
        for (int kk = 0; kk < 2; ++kk)                                        \
            _Pragma("unroll")                                                 \
            for (int m = 0; m < 4; ++m)                                       \
                _Pragma("unroll")                                             \
                for (int n = 0; n < 2; ++n)                                   \
                    acc[P][m][n] = __builtin_amdgcn_mfma_f32_16x16x32_bf16(   \
                        AH[kk][m], BH[kk][n], acc[P][m][n], 0, 0, 0);         \
        __builtin_amdgcn_s_setprio(0);                                        \
    }

    stage_tile(0);
    stage_tile(1);
    asm volatile("s_waitcnt vmcnt(8)" ::: "memory");
    __builtin_amdgcn_s_barrier();
    asm volatile("" ::: "memory");

    for (int U = 0; U < NT; ++U) {
        const char* Ab = lds + ((U & 1) << 15);
        const char* Bb = lds + 65536 + ((U & 1) << 15);

        bf16x8 a0[2][4], a1[2][4];
        bf16x8 b0[2][2], b1[2][2];

#pragma unroll
        for (int m = 0; m < 4; ++m) {
            a0[0][m] = *(const bf16x8*)(Ab + aoff + s0_16 + m * 2048);
            a0[1][m] = *(const bf16x8*)(Ab + aoff + s1_16 + m * 2048);
        }
#pragma unroll
        for (int n = 0; n < 2; ++n) {
            b0[0][n] = *(const bf16x8*)(Bb + boff + s0_16 + n * 2048);
            b0[1][n] = *(const bf16x8*)(Bb + boff + s1_16 + n * 2048);
        }
        LGKM0;

#pragma unroll
        for (int m = 0; m < 4; ++m) {
            a1[0][m] = *(const bf16x8*)(Ab + 16384 + aoff + s0_16 + m * 2048);
            a1[1][m] = *(const bf16x8*)(Ab + 16384 + aoff + s1_16 + m * 2048);
        }
        MFMAQ(0, a0, b0);
        LGKM0;

#pragma unroll
        for (int n = 0; n < 2; ++n) {
            b1[0][n] = *(const bf16x8*)(Bb + 16384 + boff + s0_16 + n * 2048);
            b1[1][n] = *(const bf16x8*)(Bb + 16384 + boff + s1_16 + n * 2048);
        }
        MFMAQ(1, a1, b0);
        LGKM0;

        __builtin_amdgcn_s_barrier();            // B1
        asm volatile("" ::: "memory");
        if (U + 2 < NT) stage_tile(U + 2);

        MFMAQ(3, a1, b1);
        MFMAQ(2, a0, b1);

        if (U + 2 < NT) asm volatile("s_waitcnt vmcnt(8)" ::: "memory");
        else            asm volatile("s_waitcnt vmcnt(0)" ::: "memory");
        __builtin_amdgcn_s_barrier();            // B2
        asm volatile("" ::: "memory");
    }
#undef MFMAQ

#pragma unroll
    for (int p = 0; p < 4; ++p) {
        const int rb = row0 + (p & 1) * 128 + wy * 64 + (lane >> 4) * 4;
        const int cb = col0 + (p >> 1) * 128 + wx * 32 + (lane & 15);
#pragma unroll
        for (int n = 0; n < 2; ++n) {
            const float bv = bias[cb + n * 16];
#pragma unroll
            for (int m = 0; m < 4; ++m) {
#pragma unroll
                for (int r = 0; r < 4; ++r) {
                    const float v = acc[p][m][n][r] + bv;
                    const size_t off = (size_t)(rb + m * 16 + r) * ldc + cb + n * 16;
                    if (OUT_BF16) ((ushort*)Cout)[off] = f2b(v);
                    else          ((float*)Cout)[off]  = v;
                }
            }
        }
    }
}

// ---------------------------------------------------------------------------
// Small 128x128 bf16 MFMA GEMM: BK=32, 4 waves, 64x64/wave, 16 KB LDS.
// ---------------------------------------------------------------------------
template<int OUT_BF16, int RELU>
__global__ __launch_bounds__(256)
void gemm_sm(const ushort* __restrict__ A, const ushort* __restrict__ Bt,
             const float* __restrict__ bias, void* __restrict__ Cout,
             int ldc, int Kdim)
{
    __shared__ __align__(16) ushort As[128 * 32];   // 8 KB
    __shared__ __align__(16) ushort Bs[128 * 32];   // 8 KB

    const int tid  = threadIdx.x;
    const int w    = tid >> 6;
    const int lane = tid & 63;

    const int gx   = gridDim.x;
    const int nwg  = gx * gridDim.y;
    const int orig = blockIdx.y * gx + blockIdx.x;
    const int q8   = nwg >> 3, r8 = nwg & 7;
    const int xcd  = orig & 7, idx8 = orig >> 3;
    const int swz  = (xcd < r8 ? xcd * (q8 + 1)
                               : r8 * (q8 + 1) + (xcd - r8) * q8) + idx8;
    const int row0 = (swz / gx) * 128;
    const int col0 = (swz % gx) * 128;
    const int wr   = w >> 1, wc = w & 1;

    f32x4 acc[4][4];
#pragma unroll
    for (int i = 0; i < 4; ++i)
#pragma unroll
        for (int j = 0; j < 4; ++j) acc[i][j] = (f32x4){0.f, 0.f, 0.f, 0.f};

    const ushort* Ag = A  + (size_t)(row0 + (tid >> 2)) * Kdim + (tid & 3) * 8;
    const ushort* Bg = Bt + (size_t)(col0 + (tid >> 2)) * Kdim + (tid & 3) * 8;

    for (int k0 = 0; k0 < Kdim; k0 += 32) {
        __syncthreads();
#pragma unroll
        for (int is = 0; is < 2; ++is)
            GLOAD_LDS16(Ag + (size_t)is * 64 * Kdim + k0,
                        (char*)As + (is * 256 + w * 64) * 16);
#pragma unroll
        for (int is = 0; is < 2; ++is)
            GLOAD_LDS16(Bg + (size_t)is * 64 * Kdim + k0,
                        (char*)Bs + (is * 256 + w * 64) * 16);
        asm volatile("s_waitcnt vmcnt(0)" ::: "memory");
        __syncthreads();

        bf16x8 a[4], b[4];
#pragma unroll
        for (int i = 0; i < 4; ++i) {
            a[i] = *(const bf16x8*)&As[(wr * 64 + i * 16 + (lane & 15)) * 32 + (lane >> 4) * 8];
            b[i] = *(const bf16x8*)&Bs[(wc * 64 + i * 16 + (lane & 15)) * 32 + (lane >> 4) * 8];
        }
#pragma unroll
        for (int i = 0; i < 4; ++i)
#pragma unroll
            for (int j = 0; j < 4; ++j)
                acc[i][j] = __builtin_amdgcn_mfma_f32_16x16x32_bf16(a[i], b[j], acc[i][j], 0, 0, 0);
    }

    float bsv[4];
#pragma unroll
    for (int j = 0; j < 4; ++j) bsv[j] = bias[col0 + wc * 64 + j * 16 + (lane & 15)];
#pragma unroll
    for (int i = 0; i < 4; ++i) {
        const int row = row0 + wr * 64 + i * 16 + (lane >> 4) * 4;
        const int col = col0 + wc * 64 + (lane & 15);
#pragma unroll
        for (int r = 0; r < 4; ++r) {
            const size_t off = (size_t)(row + r) * ldc + col;
#pragma unroll
            for (int j = 0; j < 4; ++j) {
                float vv = acc[i][j][r] + bsv[j];
                if (RELU) vv = fmaxf(vv, 0.f);
                if (OUT_BF16) ((ushort*)Cout)[off + j * 16] = f2b(vv);
                else          ((float*)Cout)[off + j * 16]  = vv;
            }
        }
    }
}

// ---------------------------------------------------------------------------
// gm_direct: gm[b][s][n] = tanh16[b][s][:] @ gl_W[s][:][n] + gl_b[s][n]
// No LDS, no transposes: B fragments built in-register from fp32 gl_W reads
// (col-coalesced 64B segments), A fragments from bf16 tanh16 via L1.
// Grid (NGg/64, Ss) = 256 blocks x 256 thr (4 waves, BN=16 per wave).
// ---------------------------------------------------------------------------
__global__ __launch_bounds__(256)
void gm_direct(const ushort* __restrict__ tanhA, const float* __restrict__ glW,
               const float* __restrict__ gl_b, float* __restrict__ gm)
{
    const int tid  = threadIdx.x;
    const int w    = tid >> 6;
    const int lane = tid & 63;
    const int s    = blockIdx.y;
    const int n    = blockIdx.x * 64 + w * 16 + (lane & 15);
    const int q8   = (lane >> 4) * 8;

    const float* Bp = glW + (size_t)s * Mm * NGg + n;   // column n, row k stride NGg

    f32x4 acc[4];
#pragma unroll
    for (int i = 0; i < 4; ++i) acc[i] = (f32x4){0.f, 0.f, 0.f, 0.f};

#pragma unroll 2
    for (int k0 = 0; k0 < Mm; k0 += 32) {
        bf16x8 a[4];
#pragma unroll
        for (int i = 0; i < 4; ++i)
            a[i] = *(const bf16x8*)&tanhA[((size_t)(i * 16 + (lane & 15)) * Ss + s) * Mm + k0 + q8];
        bf16x8 bv;
#pragma unroll
        for (int j = 0; j < 8; ++j)
            bv[j] = (short)f2b(Bp[(size_t)(k0 + q8 + j) * NGg]);
#pragma unroll
        for (int i = 0; i < 4; ++i)
            acc[i] = __builtin_amdgcn_mfma_f32_16x16x32_bf16(a[i], bv, acc[i], 0, 0, 0);
    }

    const float bb = gl_b[s * NGg + n];
#pragma unroll
    for (int i = 0; i < 4; ++i) {
#pragma unroll
        for (int r = 0; r < 4; ++r) {
            const int b = i * 16 + (lane >> 4) * 4 + r;
            gm[((size_t)b * Ss + s) * NGg + n] = acc[i][r] + bb;
        }
    }
}

// ---------------------------------------------------------------------------
// transpose + convert: out[C][R] bf16 = in[R][C] fp32   (R,C multiples of 32)
// ---------------------------------------------------------------------------
__global__ __launch_bounds__(256)
void transpose_to_bf16(const float* __restrict__ in, ushort* __restrict__ out,
                       int R, int C)
{
    __shared__ float t[32][33];
    const int c0 = blockIdx.x * 32, r0 = blockIdx.y * 32;
    const int tx = threadIdx.x & 31, ty = threadIdx.x >> 5;   // 32 x 8
#pragma unroll
    for (int i = 0; i < 32; i += 8)
        t[ty + i][tx] = in[(size_t)(r0 + ty + i) * C + c0 + tx];
    __syncthreads();
#pragma unroll
    for (int i = 0; i < 32; i += 8)
        out[(size_t)(c0 + ty + i) * R + r0 + tx] = f2b(t[tx][ty + i]);
}

// elementwise fp32 -> bf16 (n divisible by 1024)
__global__ __launch_bounds__(256)
void conv_bf16(const float* __restrict__ in, ushort* __restrict__ out)
{
    const int i = blockIdx.x * 256 + threadIdx.x;
    float4 v = ((const float4*)in)[i];
    ushort4 o;
    o.x = f2b(v.x); o.y = f2b(v.y); o.z = f2b(v.z); o.w = f2b(v.w);
    ((ushort4*)out)[i] = o;
}

// elementwise tanh(fp32) -> bf16 (n divisible by 1024)
__global__ __launch_bounds__(256)
void tanh_bf16(const float* __restrict__ in, ushort* __restrict__ out)
{
    const int i = blockIdx.x * 256 + threadIdx.x;
    float4 v = ((const float4*)in)[i];
    ushort4 o;
    o.x = f2b(tanhf(v.x)); o.y = f2b(tanhf(v.y));
    o.z = f2b(tanhf(v.z)); o.w = f2b(tanhf(v.w));
    ((ushort4*)out)[i] = o;
}

// zero-fill n floats (n divisible by 256)
__global__ __launch_bounds__(256)
void fill0(float* __restrict__ o)
{
    o[blockIdx.x * 256 + threadIdx.x] = 0.f;
}

// ---------------------------------------------------------------------------
// fuse_bias: outb[n] = sum_m bp[m] * Wkv[m][n] + bkv[n], n in [0, 2048).
// ---------------------------------------------------------------------------
__global__ __launch_bounds__(256)
void fuse_bias(const float* __restrict__ bp,
               const float* __restrict__ Wk, const float* __restrict__ Wv,
               const float* __restrict__ bk, const float* __restrict__ bv,
               float* __restrict__ outb)
{
    __shared__ float red[4][64];
    const int col = threadIdx.x & 63;
    const int mq  = threadIdx.x >> 6;
    const int n   = blockIdx.x * 64 + col;
    const float* W = (n < Mm) ? Wk : Wv;
    const int nn   = n & (Mm - 1);
    float s = 0.f;
    for (int m = mq * 256; m < mq * 256 + 256; ++m)
        s += bp[m] * W[(size_t)m * Mm + nn];
    red[mq][col] = s;
    __syncthreads();
    if (mq == 0) {
        float t = red[0][col] + red[1][col] + red[2][col] + red[3][col];
        outb[n] = t + ((n < Mm) ? bk[nn] : bv[nn]);
    }
}

// ---------------------------------------------------------------------------
// Split-K fp32 GEMM: partials P[zz][Mrows][Ncols], zz = batch*SPLITK + ks.
// ---------------------------------------------------------------------------
template<int BM, int BN, int BK, int TM, int TN, int SPLITK>
__global__ __launch_bounds__(256)
void gemm_f32_sk(const float* __restrict__ A, int lda, long long sA,
                 const float* __restrict__ B, int ldb, long long sB,
                 float* __restrict__ P, int Mrows, int Ncols, int Kdim)
{
    constexpr int TX = BN / TN;
    constexpr int TY = BM / TM;
    static_assert(TX * TY == 256, "256 threads");
    constexpr int KC4   = BK / 4;
    constexpr int A_PER = (BM * BK / 4) / 256;
    constexpr int B_PER = (BK * BN / 4) / 256;

    __shared__ float As[BK][BM + 4];
    __shared__ float Bs[BK][BN];

    const int tid = threadIdx.x;
    const int tx  = tid % TX;
    const int ty  = tid / TX;
    const int zz  = blockIdx.z;
    const int zb  = zz / SPLITK;
    const int ks  = zz % SPLITK;
    A += (long long)zb * sA;
    B += (long long)zb * sB;
    const int Kslice = Kdim / SPLITK;
    const int kbeg = ks * Kslice, kend = kbeg + Kslice;
    const int row0 = blockIdx.y * BM;
    const int col0 = blockIdx.x * BN;

    float acc[TM][TN];
#pragma unroll
    for (int i = 0; i < TM; ++i)
#pragma unroll
        for (int j = 0; j < TN; ++j) acc[i][j] = 0.f;

    for (int k0 = kbeg; k0 < kend; k0 += BK) {
        __syncthreads();
#pragma unroll
        for (int l = 0; l < A_PER; ++l) {
            int idx = tid + l * 256;
            int ar  = idx / KC4;
            int ac  = (idx % KC4) * 4;
            float4 va = *(const float4*)&A[(long long)(row0 + ar) * lda + k0 + ac];
            As[ac + 0][ar] = va.x;
            As[ac + 1][ar] = va.y;
            As[ac + 2][ar] = va.z;
            As[ac + 3][ar] = va.w;
        }
#pragma unroll
        for (int l = 0; l < B_PER; ++l) {
            int idx = tid + l * 256;
            int br  = idx / (BN / 4);
            int bc  = (idx % (BN / 4)) * 4;
            *(float4*)&Bs[br][bc] = *(const float4*)&B[(long long)(k0 + br) * ldb + col0 + bc];
        }
        __syncthreads();
#pragma unroll
        for (int k = 0; k < BK; ++k) {
            float a[TM], b[TN];
#pragma unroll
            for (int i = 0; i < TM; i += 4)
                *(float4*)&a[i] = *(const float4*)&As[k][ty * TM + i];
#pragma unroll
            for (int j = 0; j < TN; j += 4)
                *(float4*)&b[j] = *(const float4*)&Bs[k][tx * TN + j];
#pragma unroll
            for (int i = 0; i < TM; ++i)
#pragma unroll
                for (int j = 0; j < TN; ++j)
                    acc[i][j] = fmaf(a[i], b[j], acc[i][j]);
        }
    }

    float* Pz = P + (size_t)zz * Mrows * Ncols;
#pragma unroll
    for (int i = 0; i < TM; ++i) {
        const size_t prow = (size_t)(row0 + ty * TM + i) * Ncols;
#pragma unroll
        for (int j = 0; j < TN; j += 4)
            *(float4*)&Pz[prow + col0 + tx * TN + j] = *(const float4*)&acc[i][j];
    }
}

// ---------------------------------------------------------------------------
// sk_reduce: C[batch][row][col] = (relu?)( sum_ks P + bias[batch][col] )
// ---------------------------------------------------------------------------
template<int SPLITK, bool RELU>
__global__ __launch_bounds__(256)
void sk_reduce(const float* __restrict__ P, const float* __restrict__ bias,
               long long sBias, float* __restrict__ C, int ldc, long long sC,
               int pb4, int Ncols)
{
    const int gid = blockIdx.x * 256 + threadIdx.x;
    const int batch = gid / pb4;
    const int r4    = gid % pb4;
    const float4* Pb = (const float4*)P + (size_t)batch * SPLITK * pb4 + r4;
    float4 s = Pb[0];
#pragma unroll
    for (int ks = 1; ks < SPLITK; ++ks) {
        float4 p = Pb[(size_t)ks * pb4];
        s.x += p.x; s.y += p.y; s.z += p.z; s.w += p.w;
    }
    const int col = (r4 * 4) % Ncols;
    const int row = (r4 * 4) / Ncols;
    float4 bv = *(const float4*)&bias[batch * sBias + col];
    s.x += bv.x; s.y += bv.y; s.z += bv.z; s.w += bv.w;
    if (RELU) {
        s.x = fmaxf(s.x, 0.f); s.y = fmaxf(s.y, 0.f);
        s.z = fmaxf(s.z, 0.f); s.w = fmaxf(s.w, 0.f);
    }
    *(float4*)&C[(size_t)batch * sC + (size_t)row * ldc + col] = s;
}

// ---------------------------------------------------------------------------
// gi_mean[b, m] = (1/T) * sum_t relu(rl_w[m] * x_bf16[b, t, m])
// ---------------------------------------------------------------------------
__global__ __launch_bounds__(256)
void gi_reduce(const ushort* __restrict__ x, const float* __restrict__ rl_w,
               float* __restrict__ gi_mean)
{
    const int b    = blockIdx.x / (Mm / 256);
    const int mblk = blockIdx.x % (Mm / 256);
    const int m    = mblk * 256 + threadIdx.x;
    const float w  = rl_w[m];
    const ushort* xp = x + (size_t)b * Tt * Mm + m;
    float sum = 0.f;
    for (int t = 0; t < Tt; ++t)
        sum += fmaxf(w * b2f(xp[(size_t)t * Mm]), 0.f);
    gi_mean[b * Mm + m] = sum * (1.f / (float)Tt);
}

// ---------------------------------------------------------------------------
// Fused attention per (b, h), 512 threads (8 waves):
//   scores: thread t computes column t for all 8 s-rows.
//   softmax: wave w owns row w (full 64-lane reduce).
//   PV: thread (s=tid>>6, lane) accumulates att[s, lane*2 .. lane*2+1].
// q fp32 [.,S,M]; kv bf16 [.,T,2M]. No 1/sqrt(d) scale.
// ---------------------------------------------------------------------------
__global__ __launch_bounds__(512)
void attn_kernel(const float* __restrict__ q, const ushort* __restrict__ kv,
                 float* __restrict__ att)
{
    const int b = blockIdx.x / Hh;
    const int h = blockIdx.x % Hh;
    const int tid = threadIdx.x;

    __shared__ float qs[Ss][KDd];     // 4 KB
    __shared__ float sc[Ss][Tt];      // 16 KB

    // load q tile: 1024 floats, 512 threads x 2
    {
        const int idx = tid * 2;
        const int s = idx >> 7;
        const int d = idx & 127;
        float2 qv = *(const float2*)&q[((size_t)(b * Ss + s)) * Mm + h * KDd + d];
        qs[s][d] = qv.x; qs[s][d + 1] = qv.y;
    }
    __syncthreads();

    // scores: one column per thread
    {
        const int t = tid;
        const ushort* kr = kv + ((size_t)(b * Tt + t)) * (2 * Mm) + h * KDd;
        float acc[Ss];
#pragma unroll
        for (int s = 0; s < Ss; ++s) acc[s] = 0.f;
        for (int d = 0; d < KDd; d += 8) {
            uint4 u = *(const uint4*)(kr + d);
            float k0 = blo(u.x), k1 = bhi(u.x), k2 = blo(u.y), k3 = bhi(u.y);
            float k4 = blo(u.z), k5 = bhi(u.z), k6 = blo(u.w), k7 = bhi(u.w);
#pragma unroll
            for (int s = 0; s < Ss; ++s)
                acc[s] += qs[s][d + 0] * k0 + qs[s][d + 1] * k1
                        + qs[s][d + 2] * k2 + qs[s][d + 3] * k3
                        + qs[s][d + 4] * k4 + qs[s][d + 5] * k5
                        + qs[s][d + 6] * k6 + qs[s][d + 7] * k7;
        }
#pragma unroll
        for (int s = 0; s < Ss; ++s) sc[s][t] = acc[s];
    }
    __syncthreads();

    // softmax: wave s (= tid>>6) owns row s; full 64-lane reduce
    const int s    = tid >> 6;
    const int lane = tid & 63;
    float mx = -1e30f;
    for (int t = lane; t < Tt; t += 64) mx = fmaxf(mx, sc[s][t]);
#pragma unroll
    for (int m = 32; m >= 1; m >>= 1) mx = fmaxf(mx, __shfl_xor(mx, m));
    float sum = 0.f;
    for (int t = lane; t < Tt; t += 64) {
        float e = __expf(sc[s][t] - mx);
        sc[s][t] = e;
        sum += e;
    }
#pragma unroll
    for (int m = 32; m >= 1; m >>= 1) sum += __shfl_xor(sum, m);
    const float inv = 1.f / sum;
    // no barrier needed: each wave reads only its own sc row below

    // PV: thread computes att[s, d0..d0+1], d0 = lane*2
    const int d0 = lane * 2;
    const ushort* vb = kv + ((size_t)(b * Tt)) * (2 * Mm) + Mm + h * KDd + d0;
    float ax = 0.f, ay = 0.f;
    for (int t = 0; t < Tt; ++t) {
        const float p = sc[s][t];
        const unsigned u = *(const unsigned*)(vb + (size_t)t * (2 * Mm));
        ax = fmaf(p, blo(u), ax);
        ay = fmaf(p, bhi(u), ay);
    }
    float2 o = make_float2(ax * inv, ay * inv);
    *(float2*)&att[((size_t)(b * Ss + s)) * Mm + h * KDd + d0] = o;
}

// ---------------------------------------------------------------------------
__global__ __launch_bounds__(256)
void ln_add(const float* __restrict__ a, const float* __restrict__ b,
            const float* __restrict__ g, const float* __restrict__ be,
            float* __restrict__ out)
{
    const int row = blockIdx.x;
    const int tid = threadIdx.x;
    const float* ap = a + (size_t)row * Mm;
    const float* bp = b + (size_t)row * Mm;

    float4 av = *(const float4*)&ap[tid * 4];
    float4 bv = *(const float4*)&bp[tid * 4];
    float x0 = av.x + bv.x, x1 = av.y + bv.y, x2 = av.z + bv.z, x3 = av.w + bv.w;
    float s  = x0 + x1 + x2 + x3;
    float ss = x0 * x0 + x1 * x1 + x2 * x2 + x3 * x3;
#pragma unroll
    for (int m = 32; m >= 1; m >>= 1) {
        s  += __shfl_xor(s, m);
        ss += __shfl_xor(ss, m);
    }
    __shared__ float red[2][4];
    const int wid = tid >> 6;
    if ((tid & 63) == 0) { red[0][wid] = s; red[1][wid] = ss; }
    __syncthreads();
    s  = red[0][0] + red[0][1] + red[0][2] + red[0][3];
    ss = red[1][0] + red[1][1] + red[1][2] + red[1][3];
    const float mu  = s * (1.f / (float)Mm);
    const float var = ss * (1.f / (float)Mm) - mu * mu;
    const float inv = rsqrtf(var + 1e-5f);

    float4 gv = *(const float4*)&g[tid * 4];
    float4 bev = *(const float4*)&be[tid * 4];
    float4 o;
    o.x = (x0 - mu) * inv * gv.x + bev.x;
    o.y = (x1 - mu) * inv * gv.y + bev.y;
    o.z = (x2 - mu) * inv * gv.z + bev.z;
    o.w = (x3 - mu) * inv * gv.w + bev.w;
    *(float4*)&out[(size_t)row * Mm + tid * 4] = o;
}

__global__ __launch_bounds__(256)
void combine_kernel(const float* __restrict__ gm, const float* __restrict__ gi,
                    const float* __restrict__ nextm, const float* __restrict__ memory,
                    const float* __restrict__ ibp, const float* __restrict__ fbp,
                    float* __restrict__ out)
{
    const int idx = blockIdx.x * 256 + threadIdx.x;
    const int m  = idx & (Mm - 1);
    const int bs = idx >> 10;
    const int b  = bs >> 3;
    const float ib = ibp[0], fb = fbp[0];
    const float gmi = gm[(size_t)bs * NGg + m];
    const float gmf = gm[(size_t)bs * NGg + Mm + m];
    const float gii = gi[(size_t)b * NGg + m];
    const float gif = gi[(size_t)b * NGg + Mm + m];
    const float ig = 1.f / (1.f + __expf(-(gmi + gii + ib)));
    const float fg = 1.f / (1.f + __expf(-(gmf + gif + fb)));
    out[idx] = ig * tanhf(nextm[idx]) + fg * memory[idx];
}

// ---------------------------------------------------------------------------
extern "C" void kernel_launch(void* const* d_in, const int* in_sizes, int n_in,
                              void* d_out, int out_size, void* d_ws, size_t ws_size,
                              hipStream_t stream)
{
    const float* inputs = (const float*)d_in[0];
    const float* memory = (const float*)d_in[1];
    const float* Wp  = (const float*)d_in[2];
    const float* bp  = (const float*)d_in[3];
    const float* Wq  = (const float*)d_in[4];
    const float* bq  = (const float*)d_in[5];
    const float* Wk  = (const float*)d_in[6];
    const float* bk  = (const float*)d_in[7];
    const float* Wv  = (const float*)d_in[8];
    const float* bv  = (const float*)d_in[9];
    const float* Wm  = (const float*)d_in[10];
    const float* bm  = (const float*)d_in[11];
    const float* g1  = (const float*)d_in[12];
    const float* be1 = (const float*)d_in[13];
    const float* g2  = (const float*)d_in[14];
    const float* be2 = (const float*)d_in[15];
    const float* rl_w = (const float*)d_in[16];
    const float* rl_W = (const float*)d_in[17];
    const float* rl_b = (const float*)d_in[18];
    const float* gl_W = (const float*)d_in[19];
    const float* gl_b = (const float*)d_in[20];
    const float* ibp  = (const float*)d_in[21];
    const float* fbp  = (const float*)d_in[22];
    float* out = (float*)d_out;

    // allow 128 KiB dynamic LDS for the big MFMA GEMM
    (void)hipFuncSetAttribute(reinterpret_cast<const void*>(&gemm_big<1>),
                              hipFuncAttributeMaxDynamicSharedMemorySize, 131072);

    // ---- workspace layout (float units) ----
    const size_t N_SM = (size_t)Bq * Ss * Mm;     // 524,288
    float* ws = (float*)d_ws;
    float* qbuf   = ws;
    float* attb   = qbuf   + N_SM;
    float* mem1   = attb   + N_SM;
    float* mlp1   = mem1   + N_SM;    // unused slot kept
    float* mlp2   = mlp1   + N_SM;
    float* nextm  = mlp2   + N_SM;
    float* gimean = nextm  + N_SM;
    float* gibuf  = gimean + (size_t)Bq * Mm;
    float* gmbuf  = gibuf  + (size_t)Bq * NGg;
    float* skp    = gmbuf  + (size_t)Bq * Ss * NGg;       // split-K partials (gi)
    const size_t SKP_FLOATS = (size_t)8 * 512 * 1024;
    float* bkvf   = skp + SKP_FLOATS;                     // [2048] fused bias
    float* bz     = bkvf + NGg;                           // [512] zeros
    float* pconst = bz + 512;
    // bf16 constants + small bf16 activations
    ushort* ib16  = (ushort*)pconst;                      // [B*T][DIN]
    ushort* WpT   = ib16  + (size_t)Bq * Tt * DIN;        // [M][DIN]
    ushort* WkvT  = WpT   + (size_t)Mm * DIN;             // [2M][M]
    ushort* WqT   = WkvT  + (size_t)2 * Mm * Mm;          // [M][M]
    ushort* WmT   = WqT   + (size_t)Mm * Mm;              // [M][M]
    ushort* mem16 = WmT   + (size_t)Mm * Mm;              // [B*S][M]
    ushort* m116  = mem16 + N_SM;                         // bf16(mem1)
    ushort* mlp116= m116  + N_SM;                         // bf16(relu(mlp1))
    ushort* Wp16  = mlp116 + N_SM;                        // [DIN][M] bf16(Wp)
    ushort* WpkvT = Wp16  + (size_t)DIN * Mm;             // [2M][DIN] bf16(Wp@Wkv)^T
    ushort* tanh16= WpkvT + (size_t)2 * Mm * DIN;         // [B*S][M] bf16(tanh(mem))
    ushort* cend  = tanh16 + N_SM;
    // chunk region start (float*, 16B aligned)
    size_t const_u16 = (size_t)(cend - (ushort*)pconst);
    size_t const_floats = (size_t)(pconst - ws) + (const_u16 + 1) / 2;
    const_floats = (const_floats + 3) & ~(size_t)3;       // 16B align
    float* cstart = ws + const_floats;

    // per-chunk: kv bf16 (Bc*T*2M u16) + xb16 (Bc*T*M u16)
    int Bc = Bq;
    while (Bc > 1 &&
           (const_floats + (size_t)Bc * Tt * Mm * 3 / 2) * sizeof(float) > ws_size)
        Bc >>= 1;
    const size_t N_XC = (size_t)Bc * Tt * Mm;
    ushort* kvb16 = (ushort*)cstart;                      // [Bc*T][2M]
    ushort* xb16  = kvb16 + 2 * N_XC;                     // [Bc*T][M]

    const dim3 blk(256);

    // ---- precompute bf16 operands + fused weights/bias ----
    conv_bf16<<<dim3((Bq * Tt * DIN) / 1024), blk, 0, stream>>>(inputs, ib16);
    conv_bf16<<<dim3((Bq * Ss * Mm) / 1024), blk, 0, stream>>>(memory, mem16);
    conv_bf16<<<dim3((DIN * Mm) / 1024), blk, 0, stream>>>(Wp, Wp16);
    tanh_bf16<<<dim3((Bq * Ss * Mm) / 1024), blk, 0, stream>>>(memory, tanh16);
    transpose_to_bf16<<<dim3(Mm / 32, DIN / 32), blk, 0, stream>>>(Wp, WpT, DIN, Mm);
    transpose_to_bf16<<<dim3(Mm / 32, Mm / 32), blk, 0, stream>>>(Wk, WkvT, Mm, Mm);
    transpose_to_bf16<<<dim3(Mm / 32, Mm / 32), blk, 0, stream>>>(Wv, WkvT + (size_t)Mm * Mm, Mm, Mm);
    transpose_to_bf16<<<dim3(Mm / 32, Mm / 32), blk, 0, stream>>>(Wq, WqT, Mm, Mm);
    transpose_to_bf16<<<dim3(Mm / 32, Mm / 32), blk, 0, stream>>>(Wm, WmT, Mm, Mm);
    fill0<<<dim3(2), blk, 0, stream>>>(bz);

    // WpkvT[n][d] = sum_m WkvT[n][m] * Wp16[d][m]  (= (Wp@Wkv)^T, bf16)
    gemm_sm<1,0><<<dim3(DIN/128, (2*Mm)/128), blk, 0, stream>>>(
        WkvT, Wp16, bz, WpkvT, DIN, Mm);

    // bkvf[n] = bp @ Wkv[:,n] + [bk|bv][n]   (fp32, deterministic)
    fuse_bias<<<dim3(NGg / 64), blk, 0, stream>>>(bp, Wk, Wv, bk, bv, bkvf);

    // q = memory @ Wq + bq   (128^2 MFMA, fp32 out)
    gemm_sm<0,0><<<dim3(Mm/128, (Bq*Ss)/128), blk, 0, stream>>>(
        mem16, WqT, bq, qbuf, Mm, Mm);

    // ---- chunked: kv (fused, K=512), x (for gi), gi_reduce, attention ----
    for (int c0 = 0; c0 < Bq; c0 += Bc) {
        const int rows = Bc * Tt;

        // kv = bf16(inputs_c @ Wpkv + bkvf)   (N=2048, K=512)
        gemm_big<1><<<dim3((2*Mm)/256, rows/256), dim3(512), 131072, stream>>>(
            ib16 + (size_t)c0 * Tt * DIN, WpkvT, bkvf, kvb16, 2*Mm, DIN);

        // x_bf16 = bf16(inputs_c @ Wp + bp)   (only needed for gi_mean)
        gemm_big<1><<<dim3(Mm/256, rows/256), dim3(512), 131072, stream>>>(
            ib16 + (size_t)c0 * Tt * DIN, WpT, bp, xb16, Mm, DIN);

        // gi_mean_c = mean_t relu(rl_w * x)
        gi_reduce<<<dim3(Bc * (Mm/256)), blk, 0, stream>>>(
            xb16, rl_w, gimean + (size_t)c0 * Mm);

        // attention for this chunk (512-thread blocks)
        attn_kernel<<<dim3(Bc * Hh), dim3(512), 0, stream>>>(
            qbuf + (size_t)c0 * Ss * Mm, kvb16,
            attb + (size_t)c0 * Ss * Mm);
    }

    // mem1 = LN(memory + att) ; then bf16 copy for the MLP GEMMs
    ln_add<<<dim3(Bq * Ss), blk, 0, stream>>>(memory, attb, g1, be1, mem1);
    conv_bf16<<<dim3((Bq * Ss * Mm) / 1024), blk, 0, stream>>>(mem1, m116);

    // mlp1 = relu(mem1 @ Wm + bm)  -> bf16 ; mlp2 = relu(mlp1 @ Wm + bm) -> fp32
    gemm_sm<1,1><<<dim3(Mm/128, (Bq*Ss)/128), blk, 0, stream>>>(
        m116, WmT, bm, mlp116, Mm, Mm);
    gemm_sm<0,1><<<dim3(Mm/128, (Bq*Ss)/128), blk, 0, stream>>>(
        mlp116, WmT, bm, mlp2, Mm, Mm);

    // next = LN(mem1 + mlp2)
    ln_add<<<dim3(Bq * Ss), blk, 0, stream>>>(mem1, mlp2, g2, be2, nextm);

    // gm = tanh(memory) @ gl_W + gl_b   (direct bf16 MFMA, no transposes)
    gm_direct<<<dim3(NGg / 64, Ss), blk, 0, stream>>>(tanh16, gl_W, gl_b, gmbuf);

    // gi = gi_mean @ rl_W + rl_b   (split-K=8, fp32)
    gemm_f32_sk<64,64,16,4,4,8><<<dim3(NGg/64, Bq/64, 8), blk, 0, stream>>>(
        gimean, Mm, 0, rl_W, NGg, 0, skp, Bq, NGg, Mm);
    sk_reduce<8,false><<<dim3((Bq*NGg)/1024), blk, 0, stream>>>(
        skp, rl_b, 0, gibuf, NGg, 0, (Bq*NGg)/4, NGg);

    // final gates + output
    combine_kernel<<<dim3((Bq*Ss*Mm)/256), blk, 0, stream>>>(
        gmbuf, gibuf, nextm, memory, ibp, fbp, out);
}

// Round 17
// 400.290 us; speedup vs baseline: 1.2763x; 1.1590x over previous
//
#include <hip/hip_runtime.h>
#include <hip/hip_bf16.h>

// Problem constants
#define Bq   64
#define Tt   512
#define DIN  512
#define Ss   8
#define HSs  128
#define Hh   8
#define Mm   1024
#define KDd  128
#define NGg  2048

typedef __attribute__((ext_vector_type(8))) short bf16x8;
typedef __attribute__((ext_vector_type(4))) float f32x4;

__device__ __forceinline__ ushort f2b(float f) {
    union { float f; unsigned u; } v; v.f = f;
    unsigned r = v.u + 0x7fffu + ((v.u >> 16) & 1u);   // RNE
    return (ushort)(r >> 16);
}
__device__ __forceinline__ float b2f(ushort b) {
    union { unsigned u; float f; } v; v.u = ((unsigned)b) << 16;
    return v.f;
}
__device__ __forceinline__ float blo(unsigned u) {
    union { unsigned u; float f; } v; v.u = u << 16; return v.f;
}
__device__ __forceinline__ float bhi(unsigned u) {
    union { unsigned u; float f; } v; v.u = u & 0xffff0000u; return v.f;
}

#define GLOAD_LDS16(g, l) __builtin_amdgcn_global_load_lds( \
    (const __attribute__((address_space(1))) void*)(g),     \
    (__attribute__((address_space(3))) void*)(l), 16, 0, 0)

#define LGKM0 do { asm volatile("s_waitcnt lgkmcnt(0)" ::: "memory");         \
                   __builtin_amdgcn_sched_barrier(0); } while (0)

// Shared K-loop body for the 256x256 bf16 MFMA GEMM (r12 gray-code schedule).
// Defines acc[4][4][2]; uses lds, tid/wid/lane/wy/wx, row0/col0, Kdim.
#define GEMM_BODY(A_, Bt_, Kdim_)                                             \
    const int NT = (Kdim_) >> 6;                                              \
    const int sr = tid >> 3;                                                  \
    const int sq = (tid & 7) ^ (sr & 7);                                      \
    const ushort* Asrc = (A_)  + (size_t)(row0 + sr) * (Kdim_) + sq * 8;      \
    const ushort* Bsrc = (Bt_) + (size_t)(col0 + sr) * (Kdim_) + sq * 8;      \
    const int ldsw = wid * 1024;                                              \
    auto stage = [&](int isB, int U, int h) {                                 \
        const ushort* s = (isB ? Bsrc : Asrc) + (size_t)h * 128 * (Kdim_)     \
                        + (size_t)U * 64;                                     \
        char* d = lds + (isB ? 65536 : 0) + ((((U) & 1) * 2 + h) << 14) + ldsw;\
        GLOAD_LDS16(s, d);                                                    \
        GLOAD_LDS16(s + (size_t)64 * (Kdim_), d + 8192);                      \
    };                                                                        \
    auto stage_tile = [&](int U) {                                            \
        stage(0, U, 0); stage(0, U, 1); stage(1, U, 0); stage(1, U, 1);       \
    };                                                                        \
    const int l15   = lane & 15;                                              \
    const int s0_16 = (((lane >> 4)) ^ (lane & 7)) << 4;                      \
    const int s1_16 = ((4 + (lane >> 4)) ^ (lane & 7)) << 4;                  \
    const int aoff  = wy * 8192 + l15 * 128;                                  \
    const int boff  = wx * 4096 + l15 * 128;                                  \
    f32x4 acc[4][4][2];                                                       \
    _Pragma("unroll")                                                         \
    for (int p = 0; p < 4; ++p)                                               \
        _Pragma("unroll")                                                     \
        for (int m = 0; m < 4; ++m)                                           \
            _Pragma("unroll")                                                 \
            for (int n = 0; n < 2; ++n) acc[p][m][n] = (f32x4){0.f,0.f,0.f,0.f};\
    stage_tile(0);                                                            \
    stage_tile(1);                                                            \
    asm volatile("s_waitcnt vmcnt(8)" ::: "memory");                          \
    __builtin_amdgcn_s_barrier();                                             \
    asm volatile("" ::: "memory");                                            \
    for (int U = 0; U < NT; ++U) {                                            \
        const char* Ab = lds + ((U & 1) << 15);                               \
        const char* Bb = lds + 65536 + ((U & 1) << 15);                       \
        bf16x8 a0[2][4], a1[2][4];                                            \
        bf16x8 b0[2][2], b1[2][2];                                            \
        _Pragma("unroll")                                                     \
        for (int m = 0; m < 4; ++m) {                                         \
            a0[0][m] = *(const bf16x8*)(Ab + aoff + s0_16 + m * 2048);        \
            a0[1][m] = *(const bf16x8*)(Ab + aoff + s1_16 + m * 2048);        \
        }                                                                     \
        _Pragma("unroll")                                                     \
        for (int n = 0; n < 2; ++n) {                                         \
            b0[0][n] = *(const bf16x8*)(Bb + boff + s0_16 + n * 2048);        \
            b0[1][n] = *(const bf16x8*)(Bb + boff + s1_16 + n * 2048);        \
        }                                                                     \
        LGKM0;                                                                \
        _Pragma("unroll")                                                     \
        for (int m = 0; m < 4; ++m) {                                         \
            a1[0][m] = *(const bf16x8*)(Ab + 16384 + aoff + s0_16 + m * 2048);\
            a1[1][m] = *(const bf16x8*)(Ab + 16384 + aoff + s1_16 + m * 2048);\
        }                                                                     \
        MFMAQ(0, a0, b0);                                                     \
        LGKM0;                                                                \
        _Pragma("unroll")                                                     \
        for (int n = 0; n < 2; ++n) {                                         \
            b1[0][n] = *(const bf16x8*)(Bb + 16384 + boff + s0_16 + n * 2048);\
            b1[1][n] = *(const bf16x8*)(Bb + 16384 + boff + s1_16 + n * 2048);\
        }                                                                     \
        MFMAQ(1, a1, b0);                                                     \
        LGKM0;                                                                \
        __builtin_amdgcn_s_barrier();                                         \
        asm volatile("" ::: "memory");                                        \
        if (U + 2 < NT) stage_tile(U + 2);                                    \
        MFMAQ(3, a1, b1);                                                     \
        MFMAQ(2, a0, b1);                                                     \
        if (U + 2 < NT) asm volatile("s_waitcnt vmcnt(8)" ::: "memory");      \
        else            asm volatile("s_waitcnt vmcnt(0)" ::: "memory");      \
        __builtin_amdgcn_s_barrier();                                         \
        asm volatile("" ::: "memory");                                        \
    }

#define MFMAQ(P, AH, BH)                                                      \
    {                                                                         \
        __builtin_amdgcn_s_setprio(1);                                        \
        _Pragma("unroll")                                                     \
        for (int kk = 0; kk < 2; ++kk)                                        \
            _Pragma("unroll")                                                 \
            for (int m = 0; m < 4; ++m)                                       \
                _Pragma("unroll")                                             \
                for (int n = 0; n < 2; ++n)                                   \
                    acc[P][m][n] = __builtin_amdgcn_mfma_f32_16x16x32_bf16(   \
                        AH[kk][m], BH[kk][n], acc[P][m][n], 0, 0, 0);         \
        __builtin_amdgcn_s_setprio(0);                                        \
    }

// ---------------------------------------------------------------------------
// 256x256 bf16 MFMA GEMM (r12 schedule), standard C epilogue (bias, bf16/fp32).
// T1 bijective XCD swizzle; T2 both-sides XOR swizzle.
// Requires rows%256==0, N%256==0, K%64==0, K/64 >= 2.
// ---------------------------------------------------------------------------
template<int OUT_BF16>
__global__ __launch_bounds__(512)
void gemm_big(const ushort* __restrict__ A, const ushort* __restrict__ Bt,
              const float* __restrict__ bias, void* __restrict__ Cout,
              int ldc, int Kdim)
{
    extern __shared__ __align__(16) char lds[];   // 131072 bytes

    const int tid  = threadIdx.x;
    const int wid  = tid >> 6;
    const int lane = tid & 63;
    const int wy   = wid >> 2;
    const int wx   = wid & 3;

    const int gx   = gridDim.x;
    const int nwg  = gx * gridDim.y;
    const int orig = blockIdx.y * gx + blockIdx.x;
    const int q8   = nwg >> 3, r8 = nwg & 7;
    const int xcd  = orig & 7, idx8 = orig >> 3;
    const int swz  = (xcd < r8 ? xcd * (q8 + 1)
                               : r8 * (q8 + 1) + (xcd - r8) * q8) + idx8;
    const int row0 = (swz / gx) * 256;
    const int col0 = (swz % gx) * 256;

    GEMM_BODY(A, Bt, Kdim)

#pragma unroll
    for (int p = 0; p < 4; ++p) {
        const int rb = row0 + (p & 1) * 128 + wy * 64 + (lane >> 4) * 4;
        const int cb = col0 + (p >> 1) * 128 + wx * 32 + (lane & 15);
#pragma unroll
        for (int n = 0; n < 2; ++n) {
            const float bv = bias[cb + n * 16];
#pragma unroll
            for (int m = 0; m < 4; ++m) {
#pragma unroll
                for (int r = 0; r < 4; ++r) {
                    const float v = acc[p][m][n][r] + bv;
                    const size_t off = (size_t)(rb + m * 16 + r) * ldc + cb + n * 16;
                    if (OUT_BF16) ((ushort*)Cout)[off] = f2b(v);
                    else          ((float*)Cout)[off]  = v;
                }
            }
        }
    }
}

// ---------------------------------------------------------------------------
// gemm_gi: same K-loop; epilogue computes column-sums of relu(rl_w*(x))
// over the block's 256 rows (x = acc + bp) and writes one partial row
// partial[row0/256][col] — no C output at all. Deterministic (no atomics).
// ---------------------------------------------------------------------------
__global__ __launch_bounds__(512)
void gemm_gi(const ushort* __restrict__ A, const ushort* __restrict__ Bt,
             const float* __restrict__ bp, const float* __restrict__ rl_w,
             float* __restrict__ partial, int Kdim)
{
    extern __shared__ __align__(16) char lds[];   // 131072 bytes

    const int tid  = threadIdx.x;
    const int wid  = tid >> 6;
    const int lane = tid & 63;
    const int wy   = wid >> 2;
    const int wx   = wid & 3;

    const int gx   = gridDim.x;
    const int nwg  = gx * gridDim.y;
    const int orig = blockIdx.y * gx + blockIdx.x;
    const int q8   = nwg >> 3, r8 = nwg & 7;
    const int xcd  = orig & 7, idx8 = orig >> 3;
    const int swz  = (xcd < r8 ? xcd * (q8 + 1)
                               : r8 * (q8 + 1) + (xcd - r8) * q8) + idx8;
    const int row0 = (swz / gx) * 256;
    const int col0 = (swz % gx) * 256;

    GEMM_BODY(A, Bt, Kdim)

    // epilogue: per-thread column partials over its 32 rows per column group
    float csum[2][2];   // [ph = col half][n]
#pragma unroll
    for (int ph = 0; ph < 2; ++ph) {
#pragma unroll
        for (int n = 0; n < 2; ++n) {
            const int col = col0 + ph * 128 + wx * 32 + n * 16 + (lane & 15);
            const float bb = bp[col];
            const float w  = rl_w[col];
            float s = 0.f;
#pragma unroll
            for (int rh = 0; rh < 2; ++rh) {
                const int p = ph * 2 + rh;
#pragma unroll
                for (int m = 0; m < 4; ++m)
#pragma unroll
                    for (int r = 0; r < 4; ++r)
                        s += fmaxf(w * (acc[p][m][n][r] + bb), 0.f);
            }
            // reduce over the 4 row-quarter lanes (same lane&15)
            s += __shfl_xor(s, 16);
            s += __shfl_xor(s, 32);
            csum[ph][n] = s;
        }
    }
    // cross-wave (wy) reduce via LDS (K-loop LDS no longer needed)
    float* redf = (float*)lds;          // [2 wy][256 localcol]
    if ((lane >> 4) == 0) {
#pragma unroll
        for (int ph = 0; ph < 2; ++ph)
#pragma unroll
            for (int n = 0; n < 2; ++n)
                redf[wy * 256 + ph * 128 + wx * 32 + n * 16 + lane] = csum[ph][n];
    }
    __syncthreads();
    if (tid < 256)
        partial[(size_t)(row0 >> 8) * Mm + col0 + tid] = redf[tid] + redf[256 + tid];
}

// gi_finalize: gimean[b_local][m] = (partial[2b][m] + partial[2b+1][m]) / T
__global__ __launch_bounds__(256)
void gi_finalize(const float* __restrict__ partial, float* __restrict__ gimean)
{
    const int i = blockIdx.x * 256 + threadIdx.x;   // over Bc*Mm
    const int bl = i >> 10, m = i & (Mm - 1);
    gimean[i] = (partial[(size_t)(2 * bl) * Mm + m]
               + partial[(size_t)(2 * bl + 1) * Mm + m]) * (1.f / (float)Tt);
}

// ---------------------------------------------------------------------------
// Small 128x128 bf16 MFMA GEMM: BK=32, 4 waves, 64x64/wave, 16 KB LDS.
// ---------------------------------------------------------------------------
template<int OUT_BF16, int RELU>
__global__ __launch_bounds__(256)
void gemm_sm(const ushort* __restrict__ A, const ushort* __restrict__ Bt,
             const float* __restrict__ bias, void* __restrict__ Cout,
             int ldc, int Kdim)
{
    __shared__ __align__(16) ushort As[128 * 32];   // 8 KB
    __shared__ __align__(16) ushort Bs[128 * 32];   // 8 KB

    const int tid  = threadIdx.x;
    const int w    = tid >> 6;
    const int lane = tid & 63;

    const int gx   = gridDim.x;
    const int nwg  = gx * gridDim.y;
    const int orig = blockIdx.y * gx + blockIdx.x;
    const int q8   = nwg >> 3, r8 = nwg & 7;
    const int xcd  = orig & 7, idx8 = orig >> 3;
    const int swz  = (xcd < r8 ? xcd * (q8 + 1)
                               : r8 * (q8 + 1) + (xcd - r8) * q8) + idx8;
    const int row0 = (swz / gx) * 128;
    const int col0 = (swz % gx) * 128;
    const int wr   = w >> 1, wc = w & 1;

    f32x4 acc[4][4];
#pragma unroll
    for (int i = 0; i < 4; ++i)
#pragma unroll
        for (int j = 0; j < 4; ++j) acc[i][j] = (f32x4){0.f, 0.f, 0.f, 0.f};

    const ushort* Ag = A  + (size_t)(row0 + (tid >> 2)) * Kdim + (tid & 3) * 8;
    const ushort* Bg = Bt + (size_t)(col0 + (tid >> 2)) * Kdim + (tid & 3) * 8;

    for (int k0 = 0; k0 < Kdim; k0 += 32) {
        __syncthreads();
#pragma unroll
        for (int is = 0; is < 2; ++is)
            GLOAD_LDS16(Ag + (size_t)is * 64 * Kdim + k0,
                        (char*)As + (is * 256 + w * 64) * 16);
#pragma unroll
        for (int is = 0; is < 2; ++is)
            GLOAD_LDS16(Bg + (size_t)is * 64 * Kdim + k0,
                        (char*)Bs + (is * 256 + w * 64) * 16);
        asm volatile("s_waitcnt vmcnt(0)" ::: "memory");
        __syncthreads();

        bf16x8 a[4], b[4];
#pragma unroll
        for (int i = 0; i < 4; ++i) {
            a[i] = *(const bf16x8*)&As[(wr * 64 + i * 16 + (lane & 15)) * 32 + (lane >> 4) * 8];
            b[i] = *(const bf16x8*)&Bs[(wc * 64 + i * 16 + (lane & 15)) * 32 + (lane >> 4) * 8];
        }
#pragma unroll
        for (int i = 0; i < 4; ++i)
#pragma unroll
            for (int j = 0; j < 4; ++j)
                acc[i][j] = __builtin_amdgcn_mfma_f32_16x16x32_bf16(a[i], b[j], acc[i][j], 0, 0, 0);
    }

    float bsv[4];
#pragma unroll
    for (int j = 0; j < 4; ++j) bsv[j] = bias[col0 + wc * 64 + j * 16 + (lane & 15)];
#pragma unroll
    for (int i = 0; i < 4; ++i) {
        const int row = row0 + wr * 64 + i * 16 + (lane >> 4) * 4;
        const int col = col0 + wc * 64 + (lane & 15);
#pragma unroll
        for (int r = 0; r < 4; ++r) {
            const size_t off = (size_t)(row + r) * ldc + col;
#pragma unroll
            for (int j = 0; j < 4; ++j) {
                float vv = acc[i][j][r] + bsv[j];
                if (RELU) vv = fmaxf(vv, 0.f);
                if (OUT_BF16) ((ushort*)Cout)[off + j * 16] = f2b(vv);
                else          ((float*)Cout)[off + j * 16]  = vv;
            }
        }
    }
}

// ---------------------------------------------------------------------------
// gm_direct: gm[b][s][n] = tanh16[b][s][:] @ gl_W[s][:][n] + gl_b[s][n]
// ---------------------------------------------------------------------------
__global__ __launch_bounds__(256)
void gm_direct(const ushort* __restrict__ tanhA, const float* __restrict__ glW,
               const float* __restrict__ gl_b, float* __restrict__ gm)
{
    const int tid  = threadIdx.x;
    const int w    = tid >> 6;
    const int lane = tid & 63;
    const int s    = blockIdx.y;
    const int n    = blockIdx.x * 64 + w * 16 + (lane & 15);
    const int q8   = (lane >> 4) * 8;

    const float* Bp = glW + (size_t)s * Mm * NGg + n;

    f32x4 acc[4];
#pragma unroll
    for (int i = 0; i < 4; ++i) acc[i] = (f32x4){0.f, 0.f, 0.f, 0.f};

#pragma unroll 2
    for (int k0 = 0; k0 < Mm; k0 += 32) {
        bf16x8 a[4];
#pragma unroll
        for (int i = 0; i < 4; ++i)
            a[i] = *(const bf16x8*)&tanhA[((size_t)(i * 16 + (lane & 15)) * Ss + s) * Mm + k0 + q8];
        bf16x8 bv;
#pragma unroll
        for (int j = 0; j < 8; ++j)
            bv[j] = (short)f2b(Bp[(size_t)(k0 + q8 + j) * NGg]);
#pragma unroll
        for (int i = 0; i < 4; ++i)
            acc[i] = __builtin_amdgcn_mfma_f32_16x16x32_bf16(a[i], bv, acc[i], 0, 0, 0);
    }

    const float bb = gl_b[s * NGg + n];
#pragma unroll
    for (int i = 0; i < 4; ++i) {
#pragma unroll
        for (int r = 0; r < 4; ++r) {
            const int b = i * 16 + (lane >> 4) * 4 + r;
            gm[((size_t)b * Ss + s) * NGg + n] = acc[i][r] + bb;
        }
    }
}

// ---------------------------------------------------------------------------
__global__ __launch_bounds__(256)
void transpose_to_bf16(const float* __restrict__ in, ushort* __restrict__ out,
                       int R, int C)
{
    __shared__ float t[32][33];
    const int c0 = blockIdx.x * 32, r0 = blockIdx.y * 32;
    const int tx = threadIdx.x & 31, ty = threadIdx.x >> 5;   // 32 x 8
#pragma unroll
    for (int i = 0; i < 32; i += 8)
        t[ty + i][tx] = in[(size_t)(r0 + ty + i) * C + c0 + tx];
    __syncthreads();
#pragma unroll
    for (int i = 0; i < 32; i += 8)
        out[(size_t)(c0 + ty + i) * R + r0 + tx] = f2b(t[tx][ty + i]);
}

__global__ __launch_bounds__(256)
void conv_bf16(const float* __restrict__ in, ushort* __restrict__ out)
{
    const int i = blockIdx.x * 256 + threadIdx.x;
    float4 v = ((const float4*)in)[i];
    ushort4 o;
    o.x = f2b(v.x); o.y = f2b(v.y); o.z = f2b(v.z); o.w = f2b(v.w);
    ((ushort4*)out)[i] = o;
}

__global__ __launch_bounds__(256)
void tanh_bf16(const float* __restrict__ in, ushort* __restrict__ out)
{
    const int i = blockIdx.x * 256 + threadIdx.x;
    float4 v = ((const float4*)in)[i];
    ushort4 o;
    o.x = f2b(tanhf(v.x)); o.y = f2b(tanhf(v.y));
    o.z = f2b(tanhf(v.z)); o.w = f2b(tanhf(v.w));
    ((ushort4*)out)[i] = o;
}

__global__ __launch_bounds__(256)
void fill0(float* __restrict__ o)
{
    o[blockIdx.x * 256 + threadIdx.x] = 0.f;
}

// ---------------------------------------------------------------------------
// fuse_bias: outb[n] = sum_m bp[m] * Wkv[m][n] + bkv[n], n in [0, 2048).
// ---------------------------------------------------------------------------
__global__ __launch_bounds__(256)
void fuse_bias(const float* __restrict__ bp,
               const float* __restrict__ Wk, const float* __restrict__ Wv,
               const float* __restrict__ bk, const float* __restrict__ bv,
               float* __restrict__ outb)
{
    __shared__ float red[4][64];
    const int col = threadIdx.x & 63;
    const int mq  = threadIdx.x >> 6;
    const int n   = blockIdx.x * 64 + col;
    const float* W = (n < Mm) ? Wk : Wv;
    const int nn   = n & (Mm - 1);
    float s = 0.f;
    for (int m = mq * 256; m < mq * 256 + 256; ++m)
        s += bp[m] * W[(size_t)m * Mm + nn];
    red[mq][col] = s;
    __syncthreads();
    if (mq == 0) {
        float t = red[0][col] + red[1][col] + red[2][col] + red[3][col];
        outb[n] = t + ((n < Mm) ? bk[nn] : bv[nn]);
    }
}

// ---------------------------------------------------------------------------
// Split-K fp32 GEMM: partials P[zz][Mrows][Ncols], zz = batch*SPLITK + ks.
// ---------------------------------------------------------------------------
template<int BM, int BN, int BK, int TM, int TN, int SPLITK>
__global__ __launch_bounds__(256)
void gemm_f32_sk(const float* __restrict__ A, int lda, long long sA,
                 const float* __restrict__ B, int ldb, long long sB,
                 float* __restrict__ P, int Mrows, int Ncols, int Kdim)
{
    constexpr int TX = BN / TN;
    constexpr int TY = BM / TM;
    static_assert(TX * TY == 256, "256 threads");
    constexpr int KC4   = BK / 4;
    constexpr int A_PER = (BM * BK / 4) / 256;
    constexpr int B_PER = (BK * BN / 4) / 256;

    __shared__ float As[BK][BM + 4];
    __shared__ float Bs[BK][BN];

    const int tid = threadIdx.x;
    const int tx  = tid % TX;
    const int ty  = tid / TX;
    const int zz  = blockIdx.z;
    const int zb  = zz / SPLITK;
    const int ks  = zz % SPLITK;
    A += (long long)zb * sA;
    B += (long long)zb * sB;
    const int Kslice = Kdim / SPLITK;
    const int kbeg = ks * Kslice, kend = kbeg + Kslice;
    const int row0 = blockIdx.y * BM;
    const int col0 = blockIdx.x * BN;

    float acc[TM][TN];
#pragma unroll
    for (int i = 0; i < TM; ++i)
#pragma unroll
        for (int j = 0; j < TN; ++j) acc[i][j] = 0.f;

    for (int k0 = kbeg; k0 < kend; k0 += BK) {
        __syncthreads();
#pragma unroll
        for (int l = 0; l < A_PER; ++l) {
            int idx = tid + l * 256;
            int ar  = idx / KC4;
            int ac  = (idx % KC4) * 4;
            float4 va = *(const float4*)&A[(long long)(row0 + ar) * lda + k0 + ac];
            As[ac + 0][ar] = va.x;
            As[ac + 1][ar] = va.y;
            As[ac + 2][ar] = va.z;
            As[ac + 3][ar] = va.w;
        }
#pragma unroll
        for (int l = 0; l < B_PER; ++l) {
            int idx = tid + l * 256;
            int br  = idx / (BN / 4);
            int bc  = (idx % (BN / 4)) * 4;
            *(float4*)&Bs[br][bc] = *(const float4*)&B[(long long)(k0 + br) * ldb + col0 + bc];
        }
        __syncthreads();
#pragma unroll
        for (int k = 0; k < BK; ++k) {
            float a[TM], b[TN];
#pragma unroll
            for (int i = 0; i < TM; i += 4)
                *(float4*)&a[i] = *(const float4*)&As[k][ty * TM + i];
#pragma unroll
            for (int j = 0; j < TN; j += 4)
                *(float4*)&b[j] = *(const float4*)&Bs[k][tx * TN + j];
#pragma unroll
            for (int i = 0; i < TM; ++i)
#pragma unroll
                for (int j = 0; j < TN; ++j)
                    acc[i][j] = fmaf(a[i], b[j], acc[i][j]);
        }
    }

    float* Pz = P + (size_t)zz * Mrows * Ncols;
#pragma unroll
    for (int i = 0; i < TM; ++i) {
        const size_t prow = (size_t)(row0 + ty * TM + i) * Ncols;
#pragma unroll
        for (int j = 0; j < TN; j += 4)
            *(float4*)&Pz[prow + col0 + tx * TN + j] = *(const float4*)&acc[i][j];
    }
}

// ---------------------------------------------------------------------------
// sk_reduce: C[batch][row][col] = (relu?)( sum_ks P + bias[batch][col] )
// ---------------------------------------------------------------------------
template<int SPLITK, bool RELU>
__global__ __launch_bounds__(256)
void sk_reduce(const float* __restrict__ P, const float* __restrict__ bias,
               long long sBias, float* __restrict__ C, int ldc, long long sC,
               int pb4, int Ncols)
{
    const int gid = blockIdx.x * 256 + threadIdx.x;
    const int batch = gid / pb4;
    const int r4    = gid % pb4;
    const float4* Pb = (const float4*)P + (size_t)batch * SPLITK * pb4 + r4;
    float4 s = Pb[0];
#pragma unroll
    for (int ks = 1; ks < SPLITK; ++ks) {
        float4 p = Pb[(size_t)ks * pb4];
        s.x += p.x; s.y += p.y; s.z += p.z; s.w += p.w;
    }
    const int col = (r4 * 4) % Ncols;
    const int row = (r4 * 4) / Ncols;
    float4 bv = *(const float4*)&bias[batch * sBias + col];
    s.x += bv.x; s.y += bv.y; s.z += bv.z; s.w += bv.w;
    if (RELU) {
        s.x = fmaxf(s.x, 0.f); s.y = fmaxf(s.y, 0.f);
        s.z = fmaxf(s.z, 0.f); s.w = fmaxf(s.w, 0.f);
    }
    *(float4*)&C[(size_t)batch * sC + (size_t)row * ldc + col] = s;
}

// ---------------------------------------------------------------------------
// Fused attention per (b, h), 512 threads (8 waves). q fp32; kv bf16 [.,T,2M].
// ---------------------------------------------------------------------------
__global__ __launch_bounds__(512)
void attn_kernel(const float* __restrict__ q, const ushort* __restrict__ kv,
                 float* __restrict__ att)
{
    const int b = blockIdx.x / Hh;
    const int h = blockIdx.x % Hh;
    const int tid = threadIdx.x;

    __shared__ float qs[Ss][KDd];     // 4 KB
    __shared__ float sc[Ss][Tt];      // 16 KB

    {
        const int idx = tid * 2;
        const int s = idx >> 7;
        const int d = idx & 127;
        float2 qv = *(const float2*)&q[((size_t)(b * Ss + s)) * Mm + h * KDd + d];
        qs[s][d] = qv.x; qs[s][d + 1] = qv.y;
    }
    __syncthreads();

    {
        const int t = tid;
        const ushort* kr = kv + ((size_t)(b * Tt + t)) * (2 * Mm) + h * KDd;
        float acc[Ss];
#pragma unroll
        for (int s = 0; s < Ss; ++s) acc[s] = 0.f;
        for (int d = 0; d < KDd; d += 8) {
            uint4 u = *(const uint4*)(kr + d);
            float k0 = blo(u.x), k1 = bhi(u.x), k2 = blo(u.y), k3 = bhi(u.y);
            float k4 = blo(u.z), k5 = bhi(u.z), k6 = blo(u.w), k7 = bhi(u.w);
#pragma unroll
            for (int s = 0; s < Ss; ++s)
                acc[s] += qs[s][d + 0] * k0 + qs[s][d + 1] * k1
                        + qs[s][d + 2] * k2 + qs[s][d + 3] * k3
                        + qs[s][d + 4] * k4 + qs[s][d + 5] * k5
                        + qs[s][d + 6] * k6 + qs[s][d + 7] * k7;
        }
#pragma unroll
        for (int s = 0; s < Ss; ++s) sc[s][t] = acc[s];
    }
    __syncthreads();

    const int s    = tid >> 6;
    const int lane = tid & 63;
    float mx = -1e30f;
    for (int t = lane; t < Tt; t += 64) mx = fmaxf(mx, sc[s][t]);
#pragma unroll
    for (int m = 32; m >= 1; m >>= 1) mx = fmaxf(mx, __shfl_xor(mx, m));
    float sum = 0.f;
    for (int t = lane; t < Tt; t += 64) {
        float e = __expf(sc[s][t] - mx);
        sc[s][t] = e;
        sum += e;
    }
#pragma unroll
    for (int m = 32; m >= 1; m >>= 1) sum += __shfl_xor(sum, m);
    const float inv = 1.f / sum;

    const int d0 = lane * 2;
    const ushort* vb = kv + ((size_t)(b * Tt)) * (2 * Mm) + Mm + h * KDd + d0;
    float ax = 0.f, ay = 0.f;
    for (int t = 0; t < Tt; ++t) {
        const float p = sc[s][t];
        const unsigned u = *(const unsigned*)(vb + (size_t)t * (2 * Mm));
        ax = fmaf(p, blo(u), ax);
        ay = fmaf(p, bhi(u), ay);
    }
    float2 o = make_float2(ax * inv, ay * inv);
    *(float2*)&att[((size_t)(b * Ss + s)) * Mm + h * KDd + d0] = o;
}

// ---------------------------------------------------------------------------
__global__ __launch_bounds__(256)
void ln_add(const float* __restrict__ a, const float* __restrict__ b,
            const float* __restrict__ g, const float* __restrict__ be,
            float* __restrict__ out)
{
    const int row = blockIdx.x;
    const int tid = threadIdx.x;
    const float* ap = a + (size_t)row * Mm;
    const float* bp = b + (size_t)row * Mm;

    float4 av = *(const float4*)&ap[tid * 4];
    float4 bv = *(const float4*)&bp[tid * 4];
    float x0 = av.x + bv.x, x1 = av.y + bv.y, x2 = av.z + bv.z, x3 = av.w + bv.w;
    float s  = x0 + x1 + x2 + x3;
    float ss = x0 * x0 + x1 * x1 + x2 * x2 + x3 * x3;
#pragma unroll
    for (int m = 32; m >= 1; m >>= 1) {
        s  += __shfl_xor(s, m);
        ss += __shfl_xor(ss, m);
    }
    __shared__ float red[2][4];
    const int wid = tid >> 6;
    if ((tid & 63) == 0) { red[0][wid] = s; red[1][wid] = ss; }
    __syncthreads();
    s  = red[0][0] + red[0][1] + red[0][2] + red[0][3];
    ss = red[1][0] + red[1][1] + red[1][2] + red[1][3];
    const float mu  = s * (1.f / (float)Mm);
    const float var = ss * (1.f / (float)Mm) - mu * mu;
    const float inv = rsqrtf(var + 1e-5f);

    float4 gv = *(const float4*)&g[tid * 4];
    float4 bev = *(const float4*)&be[tid * 4];
    float4 o;
    o.x = (x0 - mu) * inv * gv.x + bev.x;
    o.y = (x1 - mu) * inv * gv.y + bev.y;
    o.z = (x2 - mu) * inv * gv.z + bev.z;
    o.w = (x3 - mu) * inv * gv.w + bev.w;
    *(float4*)&out[(size_t)row * Mm + tid * 4] = o;
}

__global__ __launch_bounds__(256)
void combine_kernel(const float* __restrict__ gm, const float* __restrict__ gi,
                    const float* __restrict__ nextm, const float* __restrict__ memory,
                    const float* __restrict__ ibp, const float* __restrict__ fbp,
                    float* __restrict__ out)
{
    const int idx = blockIdx.x * 256 + threadIdx.x;
    const int m  = idx & (Mm - 1);
    const int bs = idx >> 10;
    const int b  = bs >> 3;
    const float ib = ibp[0], fb = fbp[0];
    const float gmi = gm[(size_t)bs * NGg + m];
    const float gmf = gm[(size_t)bs * NGg + Mm + m];
    const float gii = gi[(size_t)b * NGg + m];
    const float gif = gi[(size_t)b * NGg + Mm + m];
    const float ig = 1.f / (1.f + __expf(-(gmi + gii + ib)));
    const float fg = 1.f / (1.f + __expf(-(gmf + gif + fb)));
    out[idx] = ig * tanhf(nextm[idx]) + fg * memory[idx];
}

// ---------------------------------------------------------------------------
extern "C" void kernel_launch(void* const* d_in, const int* in_sizes, int n_in,
                              void* d_out, int out_size, void* d_ws, size_t ws_size,
                              hipStream_t stream)
{
    const float* inputs = (const float*)d_in[0];
    const float* memory = (const float*)d_in[1];
    const float* Wp  = (const float*)d_in[2];
    const float* bp  = (const float*)d_in[3];
    const float* Wq  = (const float*)d_in[4];
    const float* bq  = (const float*)d_in[5];
    const float* Wk  = (const float*)d_in[6];
    const float* bk  = (const float*)d_in[7];
    const float* Wv  = (const float*)d_in[8];
    const float* bv  = (const float*)d_in[9];
    const float* Wm  = (const float*)d_in[10];
    const float* bm  = (const float*)d_in[11];
    const float* g1  = (const float*)d_in[12];
    const float* be1 = (const float*)d_in[13];
    const float* g2  = (const float*)d_in[14];
    const float* be2 = (const float*)d_in[15];
    const float* rl_w = (const float*)d_in[16];
    const float* rl_W = (const float*)d_in[17];
    const float* rl_b = (const float*)d_in[18];
    const float* gl_W = (const float*)d_in[19];
    const float* gl_b = (const float*)d_in[20];
    const float* ibp  = (const float*)d_in[21];
    const float* fbp  = (const float*)d_in[22];
    float* out = (float*)d_out;

    // allow 128 KiB dynamic LDS for the big MFMA GEMMs
    (void)hipFuncSetAttribute(reinterpret_cast<const void*>(&gemm_big<1>),
                              hipFuncAttributeMaxDynamicSharedMemorySize, 131072);
    (void)hipFuncSetAttribute(reinterpret_cast<const void*>(&gemm_gi),
                              hipFuncAttributeMaxDynamicSharedMemorySize, 131072);

    // ---- workspace layout (float units) ----
    const size_t N_SM = (size_t)Bq * Ss * Mm;     // 524,288
    float* ws = (float*)d_ws;
    float* qbuf   = ws;
    float* attb   = qbuf   + N_SM;
    float* mem1   = attb   + N_SM;
    float* mlp1   = mem1   + N_SM;    // unused slot kept
    float* mlp2   = mlp1   + N_SM;
    float* nextm  = mlp2   + N_SM;
    float* gimean = nextm  + N_SM;
    float* gibuf  = gimean + (size_t)Bq * Mm;
    float* gmbuf  = gibuf  + (size_t)Bq * NGg;
    float* skp    = gmbuf  + (size_t)Bq * Ss * NGg;       // split-K partials (gi)
    const size_t SKP_FLOATS = (size_t)8 * 512 * 1024;
    float* gipart = skp;                                  // reuse: [64][Mm] gi partials
    float* bkvf   = skp + SKP_FLOATS;                     // [2048] fused bias
    float* bz     = bkvf + NGg;                           // [512] zeros
    float* pconst = bz + 512;
    // bf16 constants + small bf16 activations
    ushort* ib16  = (ushort*)pconst;                      // [B*T][DIN]
    ushort* WpT   = ib16  + (size_t)Bq * Tt * DIN;        // [M][DIN]
    ushort* WkvT  = WpT   + (size_t)Mm * DIN;             // [2M][M]
    ushort* WqT   = WkvT  + (size_t)2 * Mm * Mm;          // [M][M]
    ushort* WmT   = WqT   + (size_t)Mm * Mm;              // [M][M]
    ushort* mem16 = WmT   + (size_t)Mm * Mm;              // [B*S][M]
    ushort* m116  = mem16 + N_SM;                         // bf16(mem1)
    ushort* mlp116= m116  + N_SM;                         // bf16(relu(mlp1))
    ushort* Wp16  = mlp116 + N_SM;                        // [DIN][M] bf16(Wp)
    ushort* WpkvT = Wp16  + (size_t)DIN * Mm;             // [2M][DIN] bf16(Wp@Wkv)^T
    ushort* tanh16= WpkvT + (size_t)2 * Mm * DIN;         // [B*S][M] bf16(tanh(mem))
    ushort* cend  = tanh16 + N_SM;
    // chunk region start (float*, 16B aligned)
    size_t const_u16 = (size_t)(cend - (ushort*)pconst);
    size_t const_floats = (size_t)(pconst - ws) + (const_u16 + 1) / 2;
    const_floats = (const_floats + 3) & ~(size_t)3;       // 16B align
    float* cstart = ws + const_floats;

    // per-chunk: kv bf16 (Bc*T*2M u16) — same sizing formula as before (safe)
    int Bc = Bq;
    while (Bc > 1 &&
           (const_floats + (size_t)Bc * Tt * Mm * 3 / 2) * sizeof(float) > ws_size)
        Bc >>= 1;
    ushort* kvb16 = (ushort*)cstart;                      // [Bc*T][2M]

    const dim3 blk(256);

    // ---- precompute bf16 operands + fused weights/bias ----
    conv_bf16<<<dim3((Bq * Tt * DIN) / 1024), blk, 0, stream>>>(inputs, ib16);
    conv_bf16<<<dim3((Bq * Ss * Mm) / 1024), blk, 0, stream>>>(memory, mem16);
    conv_bf16<<<dim3((DIN * Mm) / 1024), blk, 0, stream>>>(Wp, Wp16);
    tanh_bf16<<<dim3((Bq * Ss * Mm) / 1024), blk, 0, stream>>>(memory, tanh16);
    transpose_to_bf16<<<dim3(Mm / 32, DIN / 32), blk, 0, stream>>>(Wp, WpT, DIN, Mm);
    transpose_to_bf16<<<dim3(Mm / 32, Mm / 32), blk, 0, stream>>>(Wk, WkvT, Mm, Mm);
    transpose_to_bf16<<<dim3(Mm / 32, Mm / 32), blk, 0, stream>>>(Wv, WkvT + (size_t)Mm * Mm, Mm, Mm);
    transpose_to_bf16<<<dim3(Mm / 32, Mm / 32), blk, 0, stream>>>(Wq, WqT, Mm, Mm);
    transpose_to_bf16<<<dim3(Mm / 32, Mm / 32), blk, 0, stream>>>(Wm, WmT, Mm, Mm);
    fill0<<<dim3(2), blk, 0, stream>>>(bz);

    // WpkvT[n][d] = sum_m WkvT[n][m] * Wp16[d][m]  (= (Wp@Wkv)^T, bf16)
    gemm_sm<1,0><<<dim3(DIN/128, (2*Mm)/128), blk, 0, stream>>>(
        WkvT, Wp16, bz, WpkvT, DIN, Mm);

    // bkvf[n] = bp @ Wkv[:,n] + [bk|bv][n]   (fp32, deterministic)
    fuse_bias<<<dim3(NGg / 64), blk, 0, stream>>>(bp, Wk, Wv, bk, bv, bkvf);

    // q = memory @ Wq + bq   (128^2 MFMA, fp32 out)
    gemm_sm<0,0><<<dim3(Mm/128, (Bq*Ss)/128), blk, 0, stream>>>(
        mem16, WqT, bq, qbuf, Mm, Mm);

    // ---- chunked: kv (fused, K=512), gi (fused into GEMM epilogue), attn ----
    for (int c0 = 0; c0 < Bq; c0 += Bc) {
        const int rows = Bc * Tt;

        // kv = bf16(inputs_c @ Wpkv + bkvf)   (N=2048, K=512)
        gemm_big<1><<<dim3((2*Mm)/256, rows/256), dim3(512), 131072, stream>>>(
            ib16 + (size_t)c0 * Tt * DIN, WpkvT, bkvf, kvb16, 2*Mm, DIN);

        // gi partials: column sums of relu(rl_w*(inputs_c@Wp + bp)) per row-block
        gemm_gi<<<dim3(Mm/256, rows/256), dim3(512), 131072, stream>>>(
            ib16 + (size_t)c0 * Tt * DIN, WpT, bp, rl_w, gipart, DIN);
        gi_finalize<<<dim3((Bc * Mm) / 256), blk, 0, stream>>>(
            gipart, gimean + (size_t)c0 * Mm);

        // attention for this chunk (512-thread blocks)
        attn_kernel<<<dim3(Bc * Hh), dim3(512), 0, stream>>>(
            qbuf + (size_t)c0 * Ss * Mm, kvb16,
            attb + (size_t)c0 * Ss * Mm);
    }

    // mem1 = LN(memory + att) ; then bf16 copy for the MLP GEMMs
    ln_add<<<dim3(Bq * Ss), blk, 0, stream>>>(memory, attb, g1, be1, mem1);
    conv_bf16<<<dim3((Bq * Ss * Mm) / 1024), blk, 0, stream>>>(mem1, m116);

    // mlp1 = relu(mem1 @ Wm + bm)  -> bf16 ; mlp2 = relu(mlp1 @ Wm + bm) -> fp32
    gemm_sm<1,1><<<dim3(Mm/128, (Bq*Ss)/128), blk, 0, stream>>>(
        m116, WmT, bm, mlp116, Mm, Mm);
    gemm_sm<0,1><<<dim3(Mm/128, (Bq*Ss)/128), blk, 0, stream>>>(
        mlp116, WmT, bm, mlp2, Mm, Mm);

    // next = LN(mem1 + mlp2)
    ln_add<<<dim3(Bq * Ss), blk, 0, stream>>>(mem1, mlp2, g2, be2, nextm);

    // gm = tanh(memory) @ gl_W + gl_b   (direct bf16 MFMA, no transposes)
    gm_direct<<<dim3(NGg / 64, Ss), blk, 0, stream>>>(tanh16, gl_W, gl_b, gmbuf);

    // gi = gi_mean @ rl_W + rl_b   (split-K=8, fp32) — skp reused after gipart
    gemm_f32_sk<64,64,16,4,4,8><<<dim3(NGg/64, Bq/64, 8), blk, 0, stream>>>(
        gimean, Mm, 0, rl_W, NGg, 0, skp, Bq, NGg, Mm);
    sk_reduce<8,false><<<dim3((Bq*NGg)/1024), blk, 0, stream>>>(
        skp, rl_b, 0, gibuf, NGg, 0, (Bq*NGg)/4, NGg);

    // final gates + output
    combine_kernel<<<dim3((Bq*Ss*Mm)/256), blk, 0, stream>>>(
        gmbuf, gibuf, nextm, memory, ibp, fbp, out);
}